// Round 1
// baseline (811.820 us; speedup 1.0000x reference)
//
#include <hip/hip_runtime.h>

// ---------------------------------------------------------------------------
// RelGraphConv (basis-decomposed, right-norm, sum over relations) on MI355X.
//
// Rewrite: h = sum_r (segsum(x[src_r],dst_r)/deg_r) @ W_r + x@Wl + b, ReLU
// Since segment-sum commutes with the per-row matmul and the scalar deg
// normalization, precompute m_b = x @ bases_b (b=0,1); each edge then adds
//   (c[r,0]/deg_r[dst]) * m0[src] + (c[r,1]/deg_r[dst]) * m1[src]
// into out[dst]. One fused GEMM x[100000,128] @ Wcat[128,384] produces
// [m0|m1] (-> ws) and x@loop_weight + bias (-> d_out pre-activation).
// ---------------------------------------------------------------------------

#define DFEAT 128

// Build Wcat [128][384]: cols 0-127 bases[0], 128-255 bases[1], 256-383 loop_w
__global__ void build_wcat(const float* __restrict__ bases,
                           const float* __restrict__ loopw,
                           float* __restrict__ wcat) {
    int idx = blockIdx.x * blockDim.x + threadIdx.x;
    if (idx >= 128 * 384) return;
    int k = idx / 384, j = idx % 384;
    float v;
    if (j < 256) v = bases[(j >> 7) * DFEAT * DFEAT + k * DFEAT + (j & 127)];
    else         v = loopw[k * DFEAT + (j - 256)];
    wcat[idx] = v;
}

// Per-relation in-degree via fp32 atomics: deg[r*N + dst]
__global__ void degree_kernel(const int* __restrict__ dst, float* __restrict__ deg,
                              int RE, int E, int N) {
    int idx = blockIdx.x * blockDim.x + threadIdx.x;
    if (idx >= RE) return;
    int r = idx / E;
    atomicAdd(&deg[r * N + dst[idx]], 1.0f);
}

// Tiled fp32 GEMM: C[N,384] = x[N,128] @ wcat[128,384]
// cols <256 -> mAll[row*256+col]; cols >=256 -> out[row*128+(col-256)] + bias
#define BM 64
#define BN 64
#define BK 16
__global__ __launch_bounds__(256) void gemm_kernel(
    const float* __restrict__ x, const float* __restrict__ wcat,
    const float* __restrict__ bias, float* __restrict__ mAll,
    float* __restrict__ out, int Nrows) {
    __shared__ float As[BM][BK + 1];  // +1 pad: breaks 4-way bank alias on row reads
    __shared__ float Bs[BK][BN];
    const int tid = threadIdx.x;
    const int tx = tid & 15, ty = tid >> 4;
    const int row0 = blockIdx.x * BM;
    const int col0 = blockIdx.y * BN;

    float acc[4][4] = {};

    for (int k0 = 0; k0 < DFEAT; k0 += BK) {
        {   // A tile: 64x16, one float4 per thread
            int r = tid >> 2;
            int c4 = (tid & 3) << 2;
            int grow = row0 + r;
            float4 v = make_float4(0.f, 0.f, 0.f, 0.f);
            if (grow < Nrows) v = *(const float4*)&x[(size_t)grow * DFEAT + k0 + c4];
            As[r][c4 + 0] = v.x; As[r][c4 + 1] = v.y;
            As[r][c4 + 2] = v.z; As[r][c4 + 3] = v.w;
        }
        {   // B tile: 16x64, one float4 per thread (coalesced 256B/row-of-16)
            int r = tid >> 4;
            int c4 = (tid & 15) << 2;
            *(float4*)&Bs[r][c4] = *(const float4*)&wcat[(size_t)(k0 + r) * 384 + col0 + c4];
        }
        __syncthreads();
        #pragma unroll
        for (int k = 0; k < BK; ++k) {
            float a[4];
            #pragma unroll
            for (int i = 0; i < 4; ++i) a[i] = As[ty * 4 + i][k];
            float4 bv = *(const float4*)&Bs[k][tx * 4];
            float b[4] = {bv.x, bv.y, bv.z, bv.w};
            #pragma unroll
            for (int i = 0; i < 4; ++i)
                #pragma unroll
                for (int j = 0; j < 4; ++j)
                    acc[i][j] += a[i] * b[j];
        }
        __syncthreads();
    }

    const bool toM = (col0 < 256);
    const int col = col0 + tx * 4;
    #pragma unroll
    for (int i = 0; i < 4; ++i) {
        int grow = row0 + ty * 4 + i;
        if (grow >= Nrows) break;
        float4 v = make_float4(acc[i][0], acc[i][1], acc[i][2], acc[i][3]);
        if (toM) {
            *(float4*)&mAll[(size_t)grow * 256 + col] = v;
        } else {
            int c = col - 256;
            v.x += bias[c + 0]; v.y += bias[c + 1];
            v.z += bias[c + 2]; v.w += bias[c + 3];
            *(float4*)&out[(size_t)grow * DFEAT + c] = v;
        }
    }
}

// One wave (64 lanes) per edge, grid-stride. Lane l handles features l, l+64.
__global__ __launch_bounds__(256) void scatter_kernel(
    const int* __restrict__ src, const int* __restrict__ dst,
    const float* __restrict__ coeff, const float* __restrict__ deg,
    const float* __restrict__ mAll, float* __restrict__ out,
    int RE, int E, int N) {
    const int lane = threadIdx.x & 63;
    const int wave = (blockIdx.x * blockDim.x + threadIdx.x) >> 6;
    const int nwaves = (gridDim.x * blockDim.x) >> 6;
    for (int e = wave; e < RE; e += nwaves) {
        int r = e / E;
        int s = src[e];
        int d = dst[e];
        float dg = deg[r * N + d];
        float inv = 1.0f / fmaxf(dg, 1.0f);
        float c0 = coeff[r * 2 + 0] * inv;
        float c1 = coeff[r * 2 + 1] * inv;
        const float* mrow = &mAll[(size_t)s * 256];
        float v0 = c0 * mrow[lane]      + c1 * mrow[128 + lane];
        float v1 = c0 * mrow[64 + lane] + c1 * mrow[192 + lane];
        atomicAdd(&out[(size_t)d * DFEAT + lane],      v0);
        atomicAdd(&out[(size_t)d * DFEAT + 64 + lane], v1);
    }
}

__global__ void relu_kernel(float* __restrict__ out, int n4) {
    int i = blockIdx.x * blockDim.x + threadIdx.x;
    if (i >= n4) return;
    float4 v = ((float4*)out)[i];
    v.x = fmaxf(v.x, 0.f); v.y = fmaxf(v.y, 0.f);
    v.z = fmaxf(v.z, 0.f); v.w = fmaxf(v.w, 0.f);
    ((float4*)out)[i] = v;
}

extern "C" void kernel_launch(void* const* d_in, const int* in_sizes, int n_in,
                              void* d_out, int out_size, void* d_ws, size_t ws_size,
                              hipStream_t stream) {
    const float* x     = (const float*)d_in[0];
    const int*   src   = (const int*)  d_in[1];
    const int*   dst   = (const int*)  d_in[2];
    const float* coeff = (const float*)d_in[3];
    const float* bases = (const float*)d_in[4];
    const float* loopw = (const float*)d_in[5];
    const float* bias  = (const float*)d_in[6];
    float* out = (float*)d_out;

    const int N  = in_sizes[0] / DFEAT;       // 100000
    const int RE = in_sizes[1];               // R*E = 1200000
    const int B  = in_sizes[4] / (DFEAT * DFEAT);  // 2
    const int R  = in_sizes[3] / B;           // 8
    const int E  = RE / R;                    // 150000

    // workspace layout
    char* ws = (char*)d_ws;
    float* deg = (float*)ws;                             // R*N floats (3.2 MB)
    size_t off = ((size_t)R * N * sizeof(float) + 255) & ~(size_t)255;
    float* wcat = (float*)(ws + off);                    // 128*384 floats (196 KB)
    off += (size_t)128 * 384 * sizeof(float);
    float* mAll = (float*)(ws + off);                    // N*256 floats (102.4 MB)

    hipMemsetAsync(deg, 0, (size_t)R * N * sizeof(float), stream);
    build_wcat<<<(128 * 384 + 255) / 256, 256, 0, stream>>>(bases, loopw, wcat);
    degree_kernel<<<(RE + 255) / 256, 256, 0, stream>>>(dst, deg, RE, E, N);

    dim3 ggrid((N + BM - 1) / BM, 384 / BN);
    gemm_kernel<<<ggrid, 256, 0, stream>>>(x, wcat, bias, mAll, out, N);

    scatter_kernel<<<4096, 256, 0, stream>>>(src, dst, coeff, deg, mAll, out, RE, E, N);

    relu_kernel<<<(N * DFEAT / 4 + 255) / 256, 256, 0, stream>>>(out, N * DFEAT / 4);
}

// Round 2
// 625.475 us; speedup vs baseline: 1.2979x; 1.2979x over previous
//
#include <hip/hip_runtime.h>

// ---------------------------------------------------------------------------
// RelGraphConv (basis-decomposed, right-norm, sum over relations) on MI355X.
//
// h = sum_r (segsum(x[src_r],dst_r)/deg_r) @ W_r + x@Wl + b, ReLU
// R2: replace float-atomic scatter (153.6M atomics, write-through to HBM)
// with dst-bucketed gather: counting sort of edges by dst, then one wave
// per dst node accumulates in registers, single plain store + fused ReLU.
// ---------------------------------------------------------------------------

#define DFEAT 128

// Build Wcat [128][384]: cols 0-127 bases[0], 128-255 bases[1], 256-383 loop_w
__global__ void build_wcat(const float* __restrict__ bases,
                           const float* __restrict__ loopw,
                           float* __restrict__ wcat) {
    int idx = blockIdx.x * blockDim.x + threadIdx.x;
    if (idx >= 128 * 384) return;
    int k = idx / 384, j = idx % 384;
    float v;
    if (j < 256) v = bases[(j >> 7) * DFEAT * DFEAT + k * DFEAT + (j & 127)];
    else         v = loopw[k * DFEAT + (j - 256)];
    wcat[idx] = v;
}

// Per-relation in-degree (fp32, for norm) + total per-dst count (int, for CSR)
__global__ void count_kernel(const int* __restrict__ dst,
                             float* __restrict__ deg, int* __restrict__ cnt,
                             int RE, int E, int N) {
    int idx = blockIdx.x * blockDim.x + threadIdx.x;
    if (idx >= RE) return;
    int r = idx / E;
    int d = dst[idx];
    atomicAdd(&deg[r * N + d], 1.0f);
    atomicAdd(&cnt[d], 1);
}

// ---- 3-kernel exclusive scan of cnt[N] -> rowStart[N] (1024 elems/block) ----
__global__ void scan_block_sums(const int* __restrict__ cnt,
                                int* __restrict__ bsums, int N) {
    __shared__ int sdata[256];
    int b = blockIdx.x, t = threadIdx.x;
    int base = b * 1024;
    int sum = 0;
    for (int i = t; i < 1024; i += 256) {
        int idx = base + i;
        if (idx < N) sum += cnt[idx];
    }
    sdata[t] = sum; __syncthreads();
    for (int s = 128; s > 0; s >>= 1) {
        if (t < s) sdata[t] += sdata[t + s];
        __syncthreads();
    }
    if (t == 0) bsums[b] = sdata[0];
}

__global__ void scan_exclusive_small(int* __restrict__ bsums, int nb) {
    if (blockIdx.x == 0 && threadIdx.x == 0) {
        int run = 0;
        for (int i = 0; i < nb; ++i) { int v = bsums[i]; bsums[i] = run; run += v; }
    }
}

__global__ void scan_write(const int* __restrict__ cnt, const int* __restrict__ bsums,
                           int* __restrict__ rowStart, int N) {
    __shared__ int tsum[256];
    int b = blockIdx.x, t = threadIdx.x;
    int base = b * 1024 + t * 4;
    int v[4];
    int s = 0;
    #pragma unroll
    for (int i = 0; i < 4; ++i) {
        int idx = base + i;
        v[i] = s;
        int c = (idx < N) ? cnt[idx] : 0;
        s += c;
    }
    tsum[t] = s; __syncthreads();
    for (int off = 1; off < 256; off <<= 1) {
        int x = 0;
        if (t >= off) x = tsum[t - off];
        __syncthreads();
        if (t >= off) tsum[t] += x;
        __syncthreads();
    }
    int excl = (t == 0) ? 0 : tsum[t - 1];
    int boff = bsums[b];
    #pragma unroll
    for (int i = 0; i < 4; ++i) {
        int idx = base + i;
        if (idx < N) rowStart[idx] = boff + excl + v[i];
    }
}

// Place each edge in its dst bucket: ebuf[pos] = (r<<17) | src   (N < 2^17)
__global__ void fill_kernel(const int* __restrict__ src, const int* __restrict__ dst,
                            const int* __restrict__ rowStart, int* __restrict__ cursor,
                            int* __restrict__ ebuf, int RE, int E) {
    int idx = blockIdx.x * blockDim.x + threadIdx.x;
    if (idx >= RE) return;
    int r = idx / E;
    int d = dst[idx];
    int pos = rowStart[d] + atomicAdd(&cursor[d], 1);
    ebuf[pos] = (r << 17) | src[idx];
}

// Tiled fp32 GEMM: C[N,384] = x[N,128] @ wcat[128,384]
// cols <256 -> mAll[row*256+col]; cols >=256 -> out[row*128+(col-256)] + bias
#define BM 64
#define BN 64
#define BK 16
__global__ __launch_bounds__(256) void gemm_kernel(
    const float* __restrict__ x, const float* __restrict__ wcat,
    const float* __restrict__ bias, float* __restrict__ mAll,
    float* __restrict__ out, int Nrows) {
    __shared__ float As[BM][BK + 1];
    __shared__ float Bs[BK][BN];
    const int tid = threadIdx.x;
    const int tx = tid & 15, ty = tid >> 4;
    const int row0 = blockIdx.x * BM;
    const int col0 = blockIdx.y * BN;

    float acc[4][4] = {};

    for (int k0 = 0; k0 < DFEAT; k0 += BK) {
        {
            int r = tid >> 2;
            int c4 = (tid & 3) << 2;
            int grow = row0 + r;
            float4 v = make_float4(0.f, 0.f, 0.f, 0.f);
            if (grow < Nrows) v = *(const float4*)&x[(size_t)grow * DFEAT + k0 + c4];
            As[r][c4 + 0] = v.x; As[r][c4 + 1] = v.y;
            As[r][c4 + 2] = v.z; As[r][c4 + 3] = v.w;
        }
        {
            int r = tid >> 4;
            int c4 = (tid & 15) << 2;
            *(float4*)&Bs[r][c4] = *(const float4*)&wcat[(size_t)(k0 + r) * 384 + col0 + c4];
        }
        __syncthreads();
        #pragma unroll
        for (int k = 0; k < BK; ++k) {
            float a[4];
            #pragma unroll
            for (int i = 0; i < 4; ++i) a[i] = As[ty * 4 + i][k];
            float4 bv = *(const float4*)&Bs[k][tx * 4];
            float b[4] = {bv.x, bv.y, bv.z, bv.w};
            #pragma unroll
            for (int i = 0; i < 4; ++i)
                #pragma unroll
                for (int j = 0; j < 4; ++j)
                    acc[i][j] += a[i] * b[j];
        }
        __syncthreads();
    }

    const bool toM = (col0 < 256);
    const int col = col0 + tx * 4;
    #pragma unroll
    for (int i = 0; i < 4; ++i) {
        int grow = row0 + ty * 4 + i;
        if (grow >= Nrows) break;
        float4 v = make_float4(acc[i][0], acc[i][1], acc[i][2], acc[i][3]);
        if (toM) {
            *(float4*)&mAll[(size_t)grow * 256 + col] = v;
        } else {
            int c = col - 256;
            v.x += bias[c + 0]; v.y += bias[c + 1];
            v.z += bias[c + 2]; v.w += bias[c + 3];
            *(float4*)&out[(size_t)grow * DFEAT + c] = v;
        }
    }
}

// One wave per dst node: accumulate bucketed in-edges in registers, then
// out[d] = relu(out[d] + acc). Lane l handles features l and l+64.
__global__ __launch_bounds__(256) void gather_kernel(
    const int* __restrict__ ebuf, const int* __restrict__ rowStart,
    const int* __restrict__ cnt, const float* __restrict__ coeff,
    const float* __restrict__ deg, const float* __restrict__ mAll,
    float* __restrict__ out, int N) {
    const int lane = threadIdx.x & 63;
    const int wave = (blockIdx.x * blockDim.x + threadIdx.x) >> 6;
    const int nwaves = (gridDim.x * blockDim.x) >> 6;
    for (int d = wave; d < N; d += nwaves) {
        float a0 = 0.f, a1 = 0.f;
        const int start = rowStart[d];
        const int len = cnt[d];
        for (int i = 0; i < len; ++i) {
            int pk = ebuf[start + i];
            int s = pk & 131071;
            int r = pk >> 17;
            float inv = 1.0f / deg[r * N + d];   // >=1: this edge exists
            float c0 = coeff[2 * r] * inv;
            float c1 = coeff[2 * r + 1] * inv;
            const float* mrow = &mAll[(size_t)s * 256];
            a0 += c0 * mrow[lane]      + c1 * mrow[128 + lane];
            a1 += c0 * mrow[64 + lane] + c1 * mrow[192 + lane];
        }
        float* orow = &out[(size_t)d * DFEAT];
        orow[lane]      = fmaxf(orow[lane] + a0, 0.f);
        orow[64 + lane] = fmaxf(orow[64 + lane] + a1, 0.f);
    }
}

extern "C" void kernel_launch(void* const* d_in, const int* in_sizes, int n_in,
                              void* d_out, int out_size, void* d_ws, size_t ws_size,
                              hipStream_t stream) {
    const float* x     = (const float*)d_in[0];
    const int*   src   = (const int*)  d_in[1];
    const int*   dst   = (const int*)  d_in[2];
    const float* coeff = (const float*)d_in[3];
    const float* bases = (const float*)d_in[4];
    const float* loopw = (const float*)d_in[5];
    const float* bias  = (const float*)d_in[6];
    float* out = (float*)d_out;

    const int N  = in_sizes[0] / DFEAT;            // 100000
    const int RE = in_sizes[1];                    // R*E = 1200000
    const int B  = in_sizes[4] / (DFEAT * DFEAT);  // 2
    const int R  = in_sizes[3] / B;                // 8
    const int E  = RE / R;                         // 150000
    const int NB = (N + 1023) / 1024;              // scan blocks

    // workspace layout
    char* ws = (char*)d_ws;
    size_t off = 0;
    auto alloc = [&](size_t bytes) { void* p = ws + off; off = (off + bytes + 255) & ~(size_t)255; return p; };
    float* deg      = (float*)alloc((size_t)R * N * sizeof(float)); // 3.2 MB  } zeroed
    int*   cnt      = (int*)  alloc((size_t)N * sizeof(int));       // 400 KB  } zeroed
    int*   cursor   = (int*)  alloc((size_t)N * sizeof(int));       // 400 KB  } zeroed
    size_t zero_bytes = off;
    int*   rowStart = (int*)  alloc((size_t)N * sizeof(int));
    int*   bsums    = (int*)  alloc((size_t)NB * sizeof(int));
    float* wcat     = (float*)alloc((size_t)128 * 384 * sizeof(float));
    int*   ebuf     = (int*)  alloc((size_t)RE * sizeof(int));      // 4.8 MB
    float* mAll     = (float*)alloc((size_t)N * 256 * sizeof(float)); // 102.4 MB

    hipMemsetAsync(d_ws, 0, zero_bytes, stream);
    build_wcat<<<(128 * 384 + 255) / 256, 256, 0, stream>>>(bases, loopw, wcat);
    count_kernel<<<(RE + 255) / 256, 256, 0, stream>>>(dst, deg, cnt, RE, E, N);
    scan_block_sums<<<NB, 256, 0, stream>>>(cnt, bsums, N);
    scan_exclusive_small<<<1, 64, 0, stream>>>(bsums, NB);
    scan_write<<<NB, 256, 0, stream>>>(cnt, bsums, rowStart, N);
    fill_kernel<<<(RE + 255) / 256, 256, 0, stream>>>(src, dst, rowStart, cursor, ebuf, RE, E);

    dim3 ggrid((N + BM - 1) / BM, 384 / BN);
    gemm_kernel<<<ggrid, 256, 0, stream>>>(x, wcat, bias, mAll, out, N);

    gather_kernel<<<4096, 256, 0, stream>>>(ebuf, rowStart, cnt, coeff, deg, mAll, out, N);
}

// Round 4
// 507.399 us; speedup vs baseline: 1.6000x; 1.2327x over previous
//
#include <hip/hip_runtime.h>

// ---------------------------------------------------------------------------
// RelGraphConv (basis-decomposed, right-norm, sum over relations) on MI355X.
//
// h = sum_r (segsum(x[src_r],dst_r)/deg_r) @ W_r + x@Wl + b, ReLU
// R4: fix R3's staging bug — A/B LDS staging only copied the first 64 of 128
// k-elements per row (c<512, 8 segs/row instead of 16). MFMA consumed
// uninitialized LDS for k>=64 -> inf. Now 1024 chunks of 16B per tile.
// ---------------------------------------------------------------------------

#define DFEAT 128
#define LDA 136   // LDS row stride in ushorts (128 data + 8 pad)

typedef __attribute__((ext_vector_type(8))) short bf16x8;
typedef __attribute__((ext_vector_type(4))) float f32x4;

__device__ __forceinline__ ushort f2bf(float f) {
    unsigned u = __float_as_uint(f);
    u += 0x7FFF + ((u >> 16) & 1);          // round-to-nearest-even
    return (ushort)(u >> 16);
}
__device__ __forceinline__ float bf2f(unsigned h) {
    return __uint_as_float(h << 16);
}

// wcatT[j][k] bf16, j in [0,384): j<256 -> bases[j>>7][k][j&127], else loopw[k][j-256]
__global__ void build_wcatT(const float* __restrict__ bases,
                            const float* __restrict__ loopw,
                            ushort* __restrict__ wcatT) {
    int idx = blockIdx.x * blockDim.x + threadIdx.x;
    if (idx >= 384 * DFEAT) return;
    int j = idx >> 7, k = idx & 127;
    float v = (j < 256) ? bases[(j >> 7) * DFEAT * DFEAT + k * DFEAT + (j & 127)]
                        : loopw[k * DFEAT + (j - 256)];
    wcatT[j * DFEAT + k] = f2bf(v);
}

__global__ void convert_x(const float* __restrict__ x, ushort* __restrict__ xb, int n4) {
    int i = blockIdx.x * blockDim.x + threadIdx.x;
    if (i >= n4) return;
    float4 v = ((const float4*)x)[i];
    ushort4 o;
    o.x = f2bf(v.x); o.y = f2bf(v.y); o.z = f2bf(v.z); o.w = f2bf(v.w);
    ((ushort4*)xb)[i] = o;
}

// Per-relation in-degree (fp32, for norm) + total per-dst count (int, for CSR)
__global__ void count_kernel(const int* __restrict__ dst,
                             float* __restrict__ deg, int* __restrict__ cnt,
                             int RE, int E, int N) {
    int idx = blockIdx.x * blockDim.x + threadIdx.x;
    if (idx >= RE) return;
    int r = idx / E;
    int d = dst[idx];
    atomicAdd(&deg[r * N + d], 1.0f);
    atomicAdd(&cnt[d], 1);
}

// ---- exclusive scan of cnt[N] -> rowStart[N] ----
__global__ void scan_block_sums(const int* __restrict__ cnt,
                                int* __restrict__ bsums, int N) {
    __shared__ int sdata[256];
    int b = blockIdx.x, t = threadIdx.x;
    int base = b * 1024;
    int sum = 0;
    for (int i = t; i < 1024; i += 256) {
        int idx = base + i;
        if (idx < N) sum += cnt[idx];
    }
    sdata[t] = sum; __syncthreads();
    for (int s = 128; s > 0; s >>= 1) {
        if (t < s) sdata[t] += sdata[t + s];
        __syncthreads();
    }
    if (t == 0) bsums[b] = sdata[0];
}

// single-block exclusive scan of bsums[nb], nb <= 1024
__global__ void scan_mid(int* __restrict__ bsums, int nb) {
    __shared__ int s[256];
    int t = threadIdx.x;
    int base = t * 4;
    int v[4]; int sum = 0;
    #pragma unroll
    for (int i = 0; i < 4; ++i) {
        v[i] = sum;
        int c = (base + i < nb) ? bsums[base + i] : 0;
        sum += c;
    }
    s[t] = sum; __syncthreads();
    for (int off = 1; off < 256; off <<= 1) {
        int add = (t >= off) ? s[t - off] : 0;
        __syncthreads();
        s[t] += add;
        __syncthreads();
    }
    int excl = (t == 0) ? 0 : s[t - 1];
    #pragma unroll
    for (int i = 0; i < 4; ++i)
        if (base + i < nb) bsums[base + i] = excl + v[i];
}

__global__ void scan_write(const int* __restrict__ cnt, const int* __restrict__ bsums,
                           int* __restrict__ rowStart, int N) {
    __shared__ int tsum[256];
    int b = blockIdx.x, t = threadIdx.x;
    int base = b * 1024 + t * 4;
    int v[4];
    int s = 0;
    #pragma unroll
    for (int i = 0; i < 4; ++i) {
        int idx = base + i;
        v[i] = s;
        int c = (idx < N) ? cnt[idx] : 0;
        s += c;
    }
    tsum[t] = s; __syncthreads();
    for (int off = 1; off < 256; off <<= 1) {
        int x = 0;
        if (t >= off) x = tsum[t - off];
        __syncthreads();
        if (t >= off) tsum[t] += x;
        __syncthreads();
    }
    int excl = (t == 0) ? 0 : tsum[t - 1];
    int boff = bsums[b];
    #pragma unroll
    for (int i = 0; i < 4; ++i) {
        int idx = base + i;
        if (idx < N) rowStart[idx] = boff + excl + v[i];
    }
}

// Place each edge in its dst bucket: ebuf[pos] = (r<<17) | src   (N < 2^17)
__global__ void fill_kernel(const int* __restrict__ src, const int* __restrict__ dst,
                            const int* __restrict__ rowStart, int* __restrict__ cursor,
                            int* __restrict__ ebuf, int RE, int E) {
    int idx = blockIdx.x * blockDim.x + threadIdx.x;
    if (idx >= RE) return;
    int r = idx / E;
    int d = dst[idx];
    int pos = rowStart[d] + atomicAdd(&cursor[d], 1);
    ebuf[pos] = (r << 17) | src[idx];
}

// ---------------------------------------------------------------------------
// MFMA GEMM: C[N,384] = xb[N,128] @ wcat[128,384]  (bf16 in, fp32 accum)
// grid.y = by: by<4 -> mAllb (bf16, pair-interleaved), by=4,5 -> out + bias.
// Block tile 64x64, K=128 fully staged in LDS, 4 waves x (4 ksteps x 4 MFMA).
// mAllb row layout (256 ushorts): chunk l: m0[2l],m0[2l+1],m1[2l],m1[2l+1].
// ---------------------------------------------------------------------------
__global__ __launch_bounds__(256) void mfma_gemm(
    const ushort* __restrict__ xb, const ushort* __restrict__ wcatT,
    const float* __restrict__ bias, ushort* __restrict__ mAllb,
    float* __restrict__ out, int Nrows) {
    __shared__ __align__(16) ushort Als[64 * LDA];
    __shared__ __align__(16) ushort Bls[64 * LDA];
    const int tid = threadIdx.x;
    const int wave = tid >> 6, lane = tid & 63;
    const int quad = lane >> 4, l16 = lane & 15;
    const int row0 = blockIdx.x * 64;
    const int by = blockIdx.y;

    // stage A: 64 rows x 16 chunks(16B) = 1024 chunks
    for (int c = tid; c < 1024; c += 256) {
        int r = c >> 4, seg = c & 15;
        int grow = row0 + r; if (grow >= Nrows) grow = 0;
        uint4 v = *(const uint4*)(xb + (size_t)grow * DFEAT + seg * 8);
        *(uint4*)(Als + r * LDA + seg * 8) = v;
    }
    // stage B^T rows (block cols): 64 rows x 16 chunks
    for (int c = tid; c < 1024; c += 256) {
        int n = c >> 4, seg = c & 15;
        int grow;
        if (by < 4) grow = (n < 32) ? (by * 32 + n) : (128 + by * 32 + (n - 32));
        else        grow = 256 + (by - 4) * 64 + n;
        uint4 v = *(const uint4*)(wcatT + (size_t)grow * DFEAT + seg * 8);
        *(uint4*)(Bls + n * LDA + seg * 8) = v;
    }
    __syncthreads();

    f32x4 zero = {0.f, 0.f, 0.f, 0.f};
    f32x4 acc[4] = {zero, zero, zero, zero};
    #pragma unroll
    for (int t = 0; t < 4; ++t) {
        int k0 = t * 32 + quad * 8;
        bf16x8 a = *(const bf16x8*)(Als + (wave * 16 + l16) * LDA + k0);
        #pragma unroll
        for (int g = 0; g < 4; ++g) {
            bf16x8 b = *(const bf16x8*)(Bls + (g * 16 + l16) * LDA + k0);
            acc[g] = __builtin_amdgcn_mfma_f32_16x16x32_bf16(a, b, acc[g], 0, 0, 0);
        }
    }

    if (by < 4) {
        __syncthreads();                 // done reading Als; reuse as epilogue buf
        ushort* epi = Als;               // [64 rows][64 ushorts]
        #pragma unroll
        for (int g = 0; g < 4; ++g) {
            int gn = g * 16 + l16;       // block-local col 0..63
            int fl = gn & 31, bb = gn >> 5;
            int idx = (fl >> 1) * 4 + 2 * bb + (fl & 1);
            #pragma unroll
            for (int reg = 0; reg < 4; ++reg) {
                int rl = wave * 16 + quad * 4 + reg;
                epi[rl * 64 + idx] = f2bf(acc[g][reg]);
            }
        }
        __syncthreads();
        // coalesced copy-out: thread t -> row t>>2, 32B chunk t&3
        int r = tid >> 2, chunk = tid & 3;
        int grow = row0 + r;
        if (grow < Nrows) {
            uint4 v0 = *(uint4*)(epi + r * 64 + chunk * 16);
            uint4 v1 = *(uint4*)(epi + r * 64 + chunk * 16 + 8);
            ushort* dp = mAllb + (size_t)grow * 256 + by * 64 + chunk * 16;
            *(uint4*)dp = v0;
            *(uint4*)(dp + 8) = v1;
        }
    } else {
        #pragma unroll
        for (int g = 0; g < 4; ++g) {
            int c = (by - 4) * 64 + g * 16 + l16;   // 0..127
            float bv = bias[c];
            #pragma unroll
            for (int reg = 0; reg < 4; ++reg) {
                int grow = row0 + wave * 16 + quad * 4 + reg;
                if (grow < Nrows)
                    out[(size_t)grow * DFEAT + c] = acc[g][reg] + bv;
            }
        }
    }
}

// One wave per dst node; lane l owns features 2l, 2l+1.
__global__ __launch_bounds__(256) void gather_kernel(
    const int* __restrict__ ebuf, const int* __restrict__ rowStart,
    const int* __restrict__ cnt, const float* __restrict__ coeff,
    const float* __restrict__ deg, const ushort* __restrict__ mAllb,
    float* __restrict__ out, int N) {
    const int lane = threadIdx.x & 63;
    const int wave = (blockIdx.x * blockDim.x + threadIdx.x) >> 6;
    const int nwaves = (gridDim.x * blockDim.x) >> 6;
    for (int d = wave; d < N; d += nwaves) {
        float a0 = 0.f, a1 = 0.f;
        const int start = rowStart[d];
        const int len = cnt[d];
        for (int i = 0; i < len; ++i) {
            int pk = ebuf[start + i];
            int s = pk & 131071;
            int r = pk >> 17;
            float inv = 1.0f / deg[r * N + d];
            float c0 = coeff[2 * r] * inv;
            float c1 = coeff[2 * r + 1] * inv;
            uint2 u = *(const uint2*)(mAllb + (size_t)s * 256 + lane * 4);
            a0 += c0 * bf2f(u.x & 0xFFFF) + c1 * bf2f(u.y & 0xFFFF);
            a1 += c0 * bf2f(u.x >> 16)    + c1 * bf2f(u.y >> 16);
        }
        float* orow = out + (size_t)d * DFEAT + lane * 2;
        float2 p = *(float2*)orow;
        p.x = fmaxf(p.x + a0, 0.f);
        p.y = fmaxf(p.y + a1, 0.f);
        *(float2*)orow = p;
    }
}

extern "C" void kernel_launch(void* const* d_in, const int* in_sizes, int n_in,
                              void* d_out, int out_size, void* d_ws, size_t ws_size,
                              hipStream_t stream) {
    const float* x     = (const float*)d_in[0];
    const int*   src   = (const int*)  d_in[1];
    const int*   dst   = (const int*)  d_in[2];
    const float* coeff = (const float*)d_in[3];
    const float* bases = (const float*)d_in[4];
    const float* loopw = (const float*)d_in[5];
    const float* bias  = (const float*)d_in[6];
    float* out = (float*)d_out;

    const int N  = in_sizes[0] / DFEAT;            // 100000
    const int RE = in_sizes[1];                    // R*E = 1200000
    const int B  = in_sizes[4] / (DFEAT * DFEAT);  // 2
    const int R  = in_sizes[3] / B;                // 8
    const int E  = RE / R;                         // 150000
    const int NB = (N + 1023) / 1024;              // scan blocks

    // workspace layout
    char* ws = (char*)d_ws;
    size_t off = 0;
    auto alloc = [&](size_t bytes) { void* p = ws + off; off = (off + bytes + 255) & ~(size_t)255; return p; };
    float*  deg      = (float*) alloc((size_t)R * N * sizeof(float)); // } zeroed
    int*    cnt      = (int*)   alloc((size_t)N * sizeof(int));       // } zeroed
    int*    cursor   = (int*)   alloc((size_t)N * sizeof(int));       // } zeroed
    size_t zero_bytes = off;
    int*    rowStart = (int*)   alloc((size_t)N * sizeof(int));
    int*    bsums    = (int*)   alloc((size_t)NB * sizeof(int));
    ushort* wcatT    = (ushort*)alloc((size_t)384 * DFEAT * sizeof(ushort));
    ushort* xb       = (ushort*)alloc((size_t)N * DFEAT * sizeof(ushort));   // 25.6 MB
    int*    ebuf     = (int*)   alloc((size_t)RE * sizeof(int));             // 4.8 MB
    ushort* mAllb    = (ushort*)alloc((size_t)N * 256 * sizeof(ushort));     // 51.2 MB

    hipMemsetAsync(d_ws, 0, zero_bytes, stream);
    build_wcatT<<<(384 * DFEAT + 255) / 256, 256, 0, stream>>>(bases, loopw, wcatT);
    convert_x<<<(N * 32 + 255) / 256, 256, 0, stream>>>(x, xb, N * 32);
    count_kernel<<<(RE + 255) / 256, 256, 0, stream>>>(dst, deg, cnt, RE, E, N);
    scan_block_sums<<<NB, 256, 0, stream>>>(cnt, bsums, N);
    scan_mid<<<1, 256, 0, stream>>>(bsums, NB);
    scan_write<<<NB, 256, 0, stream>>>(cnt, bsums, rowStart, N);
    fill_kernel<<<(RE + 255) / 256, 256, 0, stream>>>(src, dst, rowStart, cursor, ebuf, RE, E);

    dim3 ggrid((N + 63) / 64, 6);
    mfma_gemm<<<ggrid, 256, 0, stream>>>(xb, wcatT, bias, mAllb, out, N);

    gather_kernel<<<4096, 256, 0, stream>>>(ebuf, rowStart, cnt, coeff, deg, mAllb, out, N);
}

// Round 5
// 421.278 us; speedup vs baseline: 1.9270x; 1.2044x over previous
//
#include <hip/hip_runtime.h>

// ---------------------------------------------------------------------------
// RelGraphConv (basis-decomposed, right-norm, sum over relations) on MI355X.
//
// h = sum_r (segsum(x[src_r],dst_r)/deg_r) @ W_r + x@Wl + b, ReLU
// R5: (a) gather: per-edge records (src,c0,c1) precomputed in fill; half-wave
//     per edge (uint4/lane), 2x unroll -> 4 rows in flight, ~2x less VALU;
//     (b) GEMM: convert_x fused into A-staging, all 6 col-tiles per block
//     (A staged once; was re-read 6x + separate convert pass).
// ---------------------------------------------------------------------------

#define DFEAT 128
#define LDA 136   // LDS row stride in ushorts (128 data + 8 pad)

typedef __attribute__((ext_vector_type(8))) short bf16x8;
typedef __attribute__((ext_vector_type(4))) float f32x4;

__device__ __forceinline__ ushort f2bf(float f) {
    unsigned u = __float_as_uint(f);
    u += 0x7FFF + ((u >> 16) & 1);          // round-to-nearest-even
    return (ushort)(u >> 16);
}
// packed bf16 pair -> floats: low = u<<16, high = u & 0xffff0000
__device__ __forceinline__ float bflo(unsigned u) { return __uint_as_float(u << 16); }
__device__ __forceinline__ float bfhi(unsigned u) { return __uint_as_float(u & 0xFFFF0000u); }

// wcatT[j][k] bf16, j in [0,384): j<256 -> bases[j>>7][k][j&127], else loopw[k][j-256]
__global__ void build_wcatT(const float* __restrict__ bases,
                            const float* __restrict__ loopw,
                            ushort* __restrict__ wcatT) {
    int idx = blockIdx.x * blockDim.x + threadIdx.x;
    if (idx >= 384 * DFEAT) return;
    int j = idx >> 7, k = idx & 127;
    float v = (j < 256) ? bases[(j >> 7) * DFEAT * DFEAT + k * DFEAT + (j & 127)]
                        : loopw[k * DFEAT + (j - 256)];
    wcatT[j * DFEAT + k] = f2bf(v);
}

// Per-relation in-degree (fp32, for norm) + total per-dst count (int, for CSR)
__global__ void count_kernel(const int* __restrict__ dst,
                             float* __restrict__ deg, int* __restrict__ cnt,
                             int RE, int E, int N) {
    int idx = blockIdx.x * blockDim.x + threadIdx.x;
    if (idx >= RE) return;
    int r = idx / E;
    int d = dst[idx];
    atomicAdd(&deg[r * N + d], 1.0f);
    atomicAdd(&cnt[d], 1);
}

// ---- exclusive scan of cnt[N] -> rowStart[N] ----
__global__ void scan_block_sums(const int* __restrict__ cnt,
                                int* __restrict__ bsums, int N) {
    __shared__ int sdata[256];
    int b = blockIdx.x, t = threadIdx.x;
    int base = b * 1024;
    int sum = 0;
    for (int i = t; i < 1024; i += 256) {
        int idx = base + i;
        if (idx < N) sum += cnt[idx];
    }
    sdata[t] = sum; __syncthreads();
    for (int s = 128; s > 0; s >>= 1) {
        if (t < s) sdata[t] += sdata[t + s];
        __syncthreads();
    }
    if (t == 0) bsums[b] = sdata[0];
}

// single-block exclusive scan of bsums[nb], nb <= 1024
__global__ void scan_mid(int* __restrict__ bsums, int nb) {
    __shared__ int s[256];
    int t = threadIdx.x;
    int base = t * 4;
    int v[4]; int sum = 0;
    #pragma unroll
    for (int i = 0; i < 4; ++i) {
        v[i] = sum;
        int c = (base + i < nb) ? bsums[base + i] : 0;
        sum += c;
    }
    s[t] = sum; __syncthreads();
    for (int off = 1; off < 256; off <<= 1) {
        int add = (t >= off) ? s[t - off] : 0;
        __syncthreads();
        s[t] += add;
        __syncthreads();
    }
    int excl = (t == 0) ? 0 : s[t - 1];
    #pragma unroll
    for (int i = 0; i < 4; ++i)
        if (base + i < nb) bsums[base + i] = excl + v[i];
}

__global__ void scan_write(const int* __restrict__ cnt, const int* __restrict__ bsums,
                           int* __restrict__ rowStart, int N) {
    __shared__ int tsum[256];
    int b = blockIdx.x, t = threadIdx.x;
    int base = b * 1024 + t * 4;
    int v[4];
    int s = 0;
    #pragma unroll
    for (int i = 0; i < 4; ++i) {
        int idx = base + i;
        v[i] = s;
        int c = (idx < N) ? cnt[idx] : 0;
        s += c;
    }
    tsum[t] = s; __syncthreads();
    for (int off = 1; off < 256; off <<= 1) {
        int x = 0;
        if (t >= off) x = tsum[t - off];
        __syncthreads();
        if (t >= off) tsum[t] += x;
        __syncthreads();
    }
    int excl = (t == 0) ? 0 : tsum[t - 1];
    int boff = bsums[b];
    #pragma unroll
    for (int i = 0; i < 4; ++i) {
        int idx = base + i;
        if (idx < N) rowStart[idx] = boff + excl + v[i];
    }
}

// Per-edge record in dst bucket: {src, bits(c0), bits(c1), 0}
// c0 = coeff[r][0]/deg[r][d], c1 = coeff[r][1]/deg[r][d]  (deg>=1 here)
__global__ void fill_kernel(const int* __restrict__ src, const int* __restrict__ dst,
                            const float* __restrict__ coeff, const float* __restrict__ deg,
                            const int* __restrict__ rowStart, int* __restrict__ cursor,
                            uint4* __restrict__ recs, int RE, int E, int N) {
    int idx = blockIdx.x * blockDim.x + threadIdx.x;
    if (idx >= RE) return;
    int r = idx / E;
    int d = dst[idx];
    int pos = rowStart[d] + atomicAdd(&cursor[d], 1);
    float inv = 1.0f / deg[r * N + d];
    uint4 rec;
    rec.x = (unsigned)src[idx];
    rec.y = __float_as_uint(coeff[2 * r] * inv);
    rec.z = __float_as_uint(coeff[2 * r + 1] * inv);
    rec.w = 0u;
    recs[pos] = rec;
}

// ---------------------------------------------------------------------------
// MFMA GEMM: C[N,384] = bf16(x)[N,128] @ wcat[128,384]  (fp32 accum)
// One block per 64-row tile; loops all 6 column tiles (A staged ONCE, with
// fp32->bf16 conversion fused into staging). by<4 -> mAllb (bf16 pair-
// interleaved), by=4,5 -> out = x@loopw + bias.
// mAllb row layout (256 ushorts): chunk P: m0[2P],m0[2P+1],m1[2P],m1[2P+1].
// ---------------------------------------------------------------------------
__global__ __launch_bounds__(256) void mfma_gemm(
    const float* __restrict__ x, const ushort* __restrict__ wcatT,
    const float* __restrict__ bias, ushort* __restrict__ mAllb,
    float* __restrict__ out, int Nrows) {
    __shared__ __align__(16) ushort Als[64 * LDA];
    __shared__ __align__(16) ushort Bls[64 * LDA];
    const int tid = threadIdx.x;
    const int wave = tid >> 6, lane = tid & 63;
    const int quad = lane >> 4, l16 = lane & 15;
    const int row0 = blockIdx.x * 64;

    // stage A once: 64 rows x 32 float4-chunks, convert fp32->bf16 in regs
    for (int c = tid; c < 2048; c += 256) {
        int r = c >> 5, seg = c & 31;
        int grow = row0 + r; if (grow >= Nrows) grow = 0;
        float4 v = *(const float4*)(x + (size_t)grow * DFEAT + seg * 4);
        ushort4 o = make_ushort4(f2bf(v.x), f2bf(v.y), f2bf(v.z), f2bf(v.w));
        *(ushort4*)(Als + r * LDA + seg * 4) = o;
    }

    for (int by = 0; by < 6; ++by) {
        // stage B^T tile: 64 rows x 16 chunks(16B)
        for (int c = tid; c < 1024; c += 256) {
            int n = c >> 4, seg = c & 15;
            int grow = (by < 4) ? ((n < 32) ? (by * 32 + n) : (128 + by * 32 + (n - 32)))
                                : (256 + (by - 4) * 64 + n);
            uint4 v = *(const uint4*)(wcatT + (size_t)grow * DFEAT + seg * 8);
            *(uint4*)(Bls + n * LDA + seg * 8) = v;
        }
        __syncthreads();

        f32x4 zero = {0.f, 0.f, 0.f, 0.f};
        f32x4 acc[4] = {zero, zero, zero, zero};
        #pragma unroll
        for (int t = 0; t < 4; ++t) {
            int k0 = t * 32 + quad * 8;
            bf16x8 a = *(const bf16x8*)(Als + (wave * 16 + l16) * LDA + k0);
            #pragma unroll
            for (int g = 0; g < 4; ++g) {
                bf16x8 b = *(const bf16x8*)(Bls + (g * 16 + l16) * LDA + k0);
                acc[g] = __builtin_amdgcn_mfma_f32_16x16x32_bf16(a, b, acc[g], 0, 0, 0);
            }
        }
        __syncthreads();   // all reads of Bls done before reuse/overwrite

        if (by < 4) {
            ushort* epi = Bls;               // [64 rows][64 ushorts]
            #pragma unroll
            for (int g = 0; g < 4; ++g) {
                int gn = g * 16 + l16;       // block-local col 0..63
                int fl = gn & 31, bb = gn >> 5;
                int idx = (fl >> 1) * 4 + 2 * bb + (fl & 1);
                #pragma unroll
                for (int reg = 0; reg < 4; ++reg) {
                    int rl = wave * 16 + quad * 4 + reg;
                    epi[rl * 64 + idx] = f2bf(acc[g][reg]);
                }
            }
            __syncthreads();
            // coalesced copy-out: thread t -> row t>>2, 32B chunk t&3
            int r = tid >> 2, chunk = tid & 3;
            int grow = row0 + r;
            if (grow < Nrows) {
                uint4 v0 = *(uint4*)(epi + r * 64 + chunk * 16);
                uint4 v1 = *(uint4*)(epi + r * 64 + chunk * 16 + 8);
                ushort* dp = mAllb + (size_t)grow * 256 + by * 64 + chunk * 16;
                *(uint4*)dp = v0;
                *(uint4*)(dp + 8) = v1;
            }
            __syncthreads();   // copy-out done before next B staging
        } else {
            #pragma unroll
            for (int g = 0; g < 4; ++g) {
                int c = (by - 4) * 64 + g * 16 + l16;   // 0..127
                float bv = bias[c];
                #pragma unroll
                for (int reg = 0; reg < 4; ++reg) {
                    int grow = row0 + wave * 16 + quad * 4 + reg;
                    if (grow < Nrows)
                        out[(size_t)grow * DFEAT + c] = acc[g][reg] + bv;
                }
            }
        }
    }
}

// Half-wave per edge: lanes 0-31 edge i, lanes 32-63 edge i+1; lane h owns
// features 4h..4h+3 (one uint4 = chunks 2h,2h+1). 2x unrolled -> 4 rows
// in flight. Halves combined via shfl_xor(32); low half writes float4.
__global__ __launch_bounds__(256) void gather_kernel(
    const uint4* __restrict__ recs, const int* __restrict__ rowStart,
    const int* __restrict__ cnt, const ushort* __restrict__ mAllb,
    float* __restrict__ out, int N) {
    const int lane = threadIdx.x & 63;
    const int half = lane >> 5;
    const int h = lane & 31;
    const int wave = (blockIdx.x * blockDim.x + threadIdx.x) >> 6;
    const int nwaves = (gridDim.x * blockDim.x) >> 6;
    for (int d = wave; d < N; d += nwaves) {
        float a0 = 0.f, a1 = 0.f, a2 = 0.f, a3 = 0.f;
        const int start = rowStart[d];
        const int len = cnt[d];
        int i = 0;
        for (; i + 4 <= len; i += 4) {
            uint4 rA = recs[start + i + half];
            uint4 rB = recs[start + i + 2 + half];
            uint4 uA = *(const uint4*)(mAllb + (size_t)rA.x * 256 + h * 8);
            uint4 uB = *(const uint4*)(mAllb + (size_t)rB.x * 256 + h * 8);
            float c0 = __uint_as_float(rA.y), c1 = __uint_as_float(rA.z);
            a0 += c0 * bflo(uA.x) + c1 * bflo(uA.y);
            a1 += c0 * bfhi(uA.x) + c1 * bfhi(uA.y);
            a2 += c0 * bflo(uA.z) + c1 * bflo(uA.w);
            a3 += c0 * bfhi(uA.z) + c1 * bfhi(uA.w);
            float d0 = __uint_as_float(rB.y), d1 = __uint_as_float(rB.z);
            a0 += d0 * bflo(uB.x) + d1 * bflo(uB.y);
            a1 += d0 * bfhi(uB.x) + d1 * bfhi(uB.y);
            a2 += d0 * bflo(uB.z) + d1 * bflo(uB.w);
            a3 += d0 * bfhi(uB.z) + d1 * bfhi(uB.w);
        }
        for (; i < len; i += 2) {
            int e = i + half;
            bool valid = e < len;
            uint4 r = recs[start + (valid ? e : i)];
            float c0 = valid ? __uint_as_float(r.y) : 0.f;
            float c1 = valid ? __uint_as_float(r.z) : 0.f;
            uint4 u = *(const uint4*)(mAllb + (size_t)r.x * 256 + h * 8);
            a0 += c0 * bflo(u.x) + c1 * bflo(u.y);
            a1 += c0 * bfhi(u.x) + c1 * bfhi(u.y);
            a2 += c0 * bflo(u.z) + c1 * bflo(u.w);
            a3 += c0 * bfhi(u.z) + c1 * bfhi(u.w);
        }
        a0 += __shfl_xor(a0, 32);
        a1 += __shfl_xor(a1, 32);
        a2 += __shfl_xor(a2, 32);
        a3 += __shfl_xor(a3, 32);
        if (half == 0) {
            float4* op = (float4*)(out + (size_t)d * DFEAT + h * 4);
            float4 p = *op;
            p.x = fmaxf(p.x + a0, 0.f);
            p.y = fmaxf(p.y + a1, 0.f);
            p.z = fmaxf(p.z + a2, 0.f);
            p.w = fmaxf(p.w + a3, 0.f);
            *op = p;
        }
    }
}

extern "C" void kernel_launch(void* const* d_in, const int* in_sizes, int n_in,
                              void* d_out, int out_size, void* d_ws, size_t ws_size,
                              hipStream_t stream) {
    const float* x     = (const float*)d_in[0];
    const int*   src   = (const int*)  d_in[1];
    const int*   dst   = (const int*)  d_in[2];
    const float* coeff = (const float*)d_in[3];
    const float* bases = (const float*)d_in[4];
    const float* loopw = (const float*)d_in[5];
    const float* bias  = (const float*)d_in[6];
    float* out = (float*)d_out;

    const int N  = in_sizes[0] / DFEAT;            // 100000
    const int RE = in_sizes[1];                    // R*E = 1200000
    const int B  = in_sizes[4] / (DFEAT * DFEAT);  // 2
    const int R  = in_sizes[3] / B;                // 8
    const int E  = RE / R;                         // 150000
    const int NB = (N + 1023) / 1024;              // scan blocks

    // workspace layout
    char* ws = (char*)d_ws;
    size_t off = 0;
    auto alloc = [&](size_t bytes) { void* p = ws + off; off = (off + bytes + 255) & ~(size_t)255; return p; };
    float*  deg      = (float*) alloc((size_t)R * N * sizeof(float)); // } zeroed
    int*    cnt      = (int*)   alloc((size_t)N * sizeof(int));       // } zeroed
    int*    cursor   = (int*)   alloc((size_t)N * sizeof(int));       // } zeroed
    size_t zero_bytes = off;
    int*    rowStart = (int*)   alloc((size_t)N * sizeof(int));
    int*    bsums    = (int*)   alloc((size_t)NB * sizeof(int));
    ushort* wcatT    = (ushort*)alloc((size_t)384 * DFEAT * sizeof(ushort));
    uint4*  recs     = (uint4*) alloc((size_t)RE * sizeof(uint4));           // 19.2 MB
    ushort* mAllb    = (ushort*)alloc((size_t)N * 256 * sizeof(ushort));     // 51.2 MB

    hipMemsetAsync(d_ws, 0, zero_bytes, stream);
    build_wcatT<<<(384 * DFEAT + 255) / 256, 256, 0, stream>>>(bases, loopw, wcatT);
    count_kernel<<<(RE + 255) / 256, 256, 0, stream>>>(dst, deg, cnt, RE, E, N);
    scan_block_sums<<<NB, 256, 0, stream>>>(cnt, bsums, N);
    scan_mid<<<1, 256, 0, stream>>>(bsums, NB);
    scan_write<<<NB, 256, 0, stream>>>(cnt, bsums, rowStart, N);
    fill_kernel<<<(RE + 255) / 256, 256, 0, stream>>>(src, dst, coeff, deg, rowStart,
                                                      cursor, recs, RE, E, N);

    mfma_gemm<<<(N + 63) / 64, 256, 0, stream>>>(x, wcatT, bias, mAllb, out, N);

    gather_kernel<<<4096, 256, 0, stream>>>(recs, rowStart, cnt, mAllb, out, N);
}

// Round 6
// 352.835 us; speedup vs baseline: 2.3008x; 1.1940x over previous
//
#include <hip/hip_runtime.h>

// ---------------------------------------------------------------------------
// RelGraphConv (basis-decomposed, right-norm, sum over relations) on MI355X.
//
// h = sum_r (segsum(x[src_r],dst_r)/deg_r) @ W_r + x@Wl + b, ReLU
// R6: counting-sort atomic diet.
//  - count pass: deg int atomics only; atomicAdd's RETURN VALUE = per-(r,d)
//    rank, stored coalesced (ushort). cnt[d]=sum_r deg[r][d] derived in scan.
//  - scan pass also emits offsetR[r][d] (exclusive prefix of deg over r).
//  - fill pass: pos = rowStart[d] + offsetR[r][d] + rank[idx] -> NO atomics.
// ---------------------------------------------------------------------------

#define DFEAT 128
#define LDA 136   // LDS row stride in ushorts (128 data + 8 pad)
#define NREL 8

typedef __attribute__((ext_vector_type(8))) short bf16x8;
typedef __attribute__((ext_vector_type(4))) float f32x4;

__device__ __forceinline__ ushort f2bf(float f) {
    unsigned u = __float_as_uint(f);
    u += 0x7FFF + ((u >> 16) & 1);          // round-to-nearest-even
    return (ushort)(u >> 16);
}
// packed bf16 pair -> floats: low = u<<16, high = u & 0xffff0000
__device__ __forceinline__ float bflo(unsigned u) { return __uint_as_float(u << 16); }
__device__ __forceinline__ float bfhi(unsigned u) { return __uint_as_float(u & 0xFFFF0000u); }

// wcatT[j][k] bf16, j in [0,384): j<256 -> bases[j>>7][k][j&127], else loopw[k][j-256]
__global__ void build_wcatT(const float* __restrict__ bases,
                            const float* __restrict__ loopw,
                            ushort* __restrict__ wcatT) {
    int idx = blockIdx.x * blockDim.x + threadIdx.x;
    if (idx >= 384 * DFEAT) return;
    int j = idx >> 7, k = idx & 127;
    float v = (j < 256) ? bases[(j >> 7) * DFEAT * DFEAT + k * DFEAT + (j & 127)]
                        : loopw[k * DFEAT + (j - 256)];
    wcatT[j * DFEAT + k] = f2bf(v);
}

// deg[r*N+d] int atomics; return value = rank of this edge within (r,d).
__global__ void count_rank_kernel(const int* __restrict__ dst,
                                  int* __restrict__ deg, ushort* __restrict__ rank,
                                  int RE, int E, int N) {
    int idx = blockIdx.x * blockDim.x + threadIdx.x;
    if (idx >= RE) return;
    int r = idx / E;
    int d = dst[idx];
    int old = atomicAdd(&deg[r * N + d], 1);
    rank[idx] = (ushort)old;
}

// Per 1024-node chunk: cnt[d] = sum_r deg[r][d]; offsetR[r][d] = prefix over r;
// bsums[b] = sum of cnt in chunk.
__global__ void scan_block_sums(const int* __restrict__ deg, int* __restrict__ cnt,
                                ushort* __restrict__ offsetR, int* __restrict__ bsums,
                                int N) {
    __shared__ int sdata[256];
    int b = blockIdx.x, t = threadIdx.x;
    int sum = 0;
    for (int j = 0; j < 4; ++j) {
        int idx = b * 1024 + j * 256 + t;
        if (idx < N) {
            int tot = 0;
            #pragma unroll
            for (int r = 0; r < NREL; ++r) {
                int dv = deg[r * N + idx];
                offsetR[r * N + idx] = (ushort)tot;
                tot += dv;
            }
            cnt[idx] = tot;
            sum += tot;
        }
    }
    sdata[t] = sum; __syncthreads();
    for (int s = 128; s > 0; s >>= 1) {
        if (t < s) sdata[t] += sdata[t + s];
        __syncthreads();
    }
    if (t == 0) bsums[b] = sdata[0];
}

// single-block exclusive scan of bsums[nb], nb <= 1024
__global__ void scan_mid(int* __restrict__ bsums, int nb) {
    __shared__ int s[256];
    int t = threadIdx.x;
    int base = t * 4;
    int v[4]; int sum = 0;
    #pragma unroll
    for (int i = 0; i < 4; ++i) {
        v[i] = sum;
        int c = (base + i < nb) ? bsums[base + i] : 0;
        sum += c;
    }
    s[t] = sum; __syncthreads();
    for (int off = 1; off < 256; off <<= 1) {
        int add = (t >= off) ? s[t - off] : 0;
        __syncthreads();
        s[t] += add;
        __syncthreads();
    }
    int excl = (t == 0) ? 0 : s[t - 1];
    #pragma unroll
    for (int i = 0; i < 4; ++i)
        if (base + i < nb) bsums[base + i] = excl + v[i];
}

__global__ void scan_write(const int* __restrict__ cnt, const int* __restrict__ bsums,
                           int* __restrict__ rowStart, int N) {
    __shared__ int tsum[256];
    int b = blockIdx.x, t = threadIdx.x;
    int base = b * 1024 + t * 4;
    int v[4];
    int s = 0;
    #pragma unroll
    for (int i = 0; i < 4; ++i) {
        int idx = base + i;
        v[i] = s;
        int c = (idx < N) ? cnt[idx] : 0;
        s += c;
    }
    tsum[t] = s; __syncthreads();
    for (int off = 1; off < 256; off <<= 1) {
        int x = 0;
        if (t >= off) x = tsum[t - off];
        __syncthreads();
        if (t >= off) tsum[t] += x;
        __syncthreads();
    }
    int excl = (t == 0) ? 0 : tsum[t - 1];
    int boff = bsums[b];
    #pragma unroll
    for (int i = 0; i < 4; ++i) {
        int idx = base + i;
        if (idx < N) rowStart[idx] = boff + excl + v[i];
    }
}

// Atomic-free placement: pos = rowStart[d] + offsetR[r][d] + rank[idx].
// Record: {src, bits(c0), bits(c1), 0}, c_b = coeff[r][b]/deg[r][d].
__global__ void fill_kernel(const int* __restrict__ src, const int* __restrict__ dst,
                            const float* __restrict__ coeff, const int* __restrict__ deg,
                            const ushort* __restrict__ rank, const ushort* __restrict__ offsetR,
                            const int* __restrict__ rowStart,
                            uint4* __restrict__ recs, int RE, int E, int N) {
    int idx = blockIdx.x * blockDim.x + threadIdx.x;
    if (idx >= RE) return;
    int r = idx / E;
    int d = dst[idx];
    int pos = rowStart[d] + offsetR[r * N + d] + rank[idx];
    float inv = 1.0f / (float)deg[r * N + d];
    uint4 rec;
    rec.x = (unsigned)src[idx];
    rec.y = __float_as_uint(coeff[2 * r] * inv);
    rec.z = __float_as_uint(coeff[2 * r + 1] * inv);
    rec.w = 0u;
    recs[pos] = rec;
}

// ---------------------------------------------------------------------------
// MFMA GEMM: C[N,384] = bf16(x)[N,128] @ wcat[128,384]  (fp32 accum)
// One block per 64-row tile; loops all 6 column tiles (A staged once, with
// fp32->bf16 conversion fused into staging). by<4 -> mAllb (bf16 pair-
// interleaved), by=4,5 -> out = x@loopw + bias.
// mAllb row layout (256 ushorts): chunk P: m0[2P],m0[2P+1],m1[2P],m1[2P+1].
// ---------------------------------------------------------------------------
__global__ __launch_bounds__(256) void mfma_gemm(
    const float* __restrict__ x, const ushort* __restrict__ wcatT,
    const float* __restrict__ bias, ushort* __restrict__ mAllb,
    float* __restrict__ out, int Nrows) {
    __shared__ __align__(16) ushort Als[64 * LDA];
    __shared__ __align__(16) ushort Bls[64 * LDA];
    const int tid = threadIdx.x;
    const int wave = tid >> 6, lane = tid & 63;
    const int quad = lane >> 4, l16 = lane & 15;
    const int row0 = blockIdx.x * 64;

    // stage A once: 64 rows x 32 float4-chunks, convert fp32->bf16 in regs
    for (int c = tid; c < 2048; c += 256) {
        int r = c >> 5, seg = c & 31;
        int grow = row0 + r; if (grow >= Nrows) grow = 0;
        float4 v = *(const float4*)(x + (size_t)grow * DFEAT + seg * 4);
        ushort4 o = make_ushort4(f2bf(v.x), f2bf(v.y), f2bf(v.z), f2bf(v.w));
        *(ushort4*)(Als + r * LDA + seg * 4) = o;
    }

    for (int by = 0; by < 6; ++by) {
        // stage B^T tile: 64 rows x 16 chunks(16B)
        for (int c = tid; c < 1024; c += 256) {
            int n = c >> 4, seg = c & 15;
            int grow = (by < 4) ? ((n < 32) ? (by * 32 + n) : (128 + by * 32 + (n - 32)))
                                : (256 + (by - 4) * 64 + n);
            uint4 v = *(const uint4*)(wcatT + (size_t)grow * DFEAT + seg * 8);
            *(uint4*)(Bls + n * LDA + seg * 8) = v;
        }
        __syncthreads();

        f32x4 zero = {0.f, 0.f, 0.f, 0.f};
        f32x4 acc[4] = {zero, zero, zero, zero};
        #pragma unroll
        for (int t = 0; t < 4; ++t) {
            int k0 = t * 32 + quad * 8;
            bf16x8 a = *(const bf16x8*)(Als + (wave * 16 + l16) * LDA + k0);
            #pragma unroll
            for (int g = 0; g < 4; ++g) {
                bf16x8 b = *(const bf16x8*)(Bls + (g * 16 + l16) * LDA + k0);
                acc[g] = __builtin_amdgcn_mfma_f32_16x16x32_bf16(a, b, acc[g], 0, 0, 0);
            }
        }
        __syncthreads();   // all reads of Bls done before reuse/overwrite

        if (by < 4) {
            ushort* epi = Bls;               // [64 rows][64 ushorts]
            #pragma unroll
            for (int g = 0; g < 4; ++g) {
                int gn = g * 16 + l16;       // block-local col 0..63
                int fl = gn & 31, bb = gn >> 5;
                int idx = (fl >> 1) * 4 + 2 * bb + (fl & 1);
                #pragma unroll
                for (int reg = 0; reg < 4; ++reg) {
                    int rl = wave * 16 + quad * 4 + reg;
                    epi[rl * 64 + idx] = f2bf(acc[g][reg]);
                }
            }
            __syncthreads();
            // coalesced copy-out: thread t -> row t>>2, 32B chunk t&3
            int r = tid >> 2, chunk = tid & 3;
            int grow = row0 + r;
            if (grow < Nrows) {
                uint4 v0 = *(uint4*)(epi + r * 64 + chunk * 16);
                uint4 v1 = *(uint4*)(epi + r * 64 + chunk * 16 + 8);
                ushort* dp = mAllb + (size_t)grow * 256 + by * 64 + chunk * 16;
                *(uint4*)dp = v0;
                *(uint4*)(dp + 8) = v1;
            }
            __syncthreads();   // copy-out done before next B staging
        } else {
            #pragma unroll
            for (int g = 0; g < 4; ++g) {
                int c = (by - 4) * 64 + g * 16 + l16;   // 0..127
                float bv = bias[c];
                #pragma unroll
                for (int reg = 0; reg < 4; ++reg) {
                    int grow = row0 + wave * 16 + quad * 4 + reg;
                    if (grow < Nrows)
                        out[(size_t)grow * DFEAT + c] = acc[g][reg] + bv;
                }
            }
        }
    }
}

// Half-wave per edge: lanes 0-31 edge i, lanes 32-63 edge i+1; lane h owns
// features 4h..4h+3 (one uint4 = chunks 2h,2h+1). 2x unrolled -> 4 rows
// in flight. Halves combined via shfl_xor(32); low half writes float4.
__global__ __launch_bounds__(256) void gather_kernel(
    const uint4* __restrict__ recs, const int* __restrict__ rowStart,
    const int* __restrict__ cnt, const ushort* __restrict__ mAllb,
    float* __restrict__ out, int N) {
    const int lane = threadIdx.x & 63;
    const int half = lane >> 5;
    const int h = lane & 31;
    const int wave = (blockIdx.x * blockDim.x + threadIdx.x) >> 6;
    const int nwaves = (gridDim.x * blockDim.x) >> 6;
    for (int d = wave; d < N; d += nwaves) {
        float a0 = 0.f, a1 = 0.f, a2 = 0.f, a3 = 0.f;
        const int start = rowStart[d];
        const int len = cnt[d];
        int i = 0;
        for (; i + 4 <= len; i += 4) {
            uint4 rA = recs[start + i + half];
            uint4 rB = recs[start + i + 2 + half];
            uint4 uA = *(const uint4*)(mAllb + (size_t)rA.x * 256 + h * 8);
            uint4 uB = *(const uint4*)(mAllb + (size_t)rB.x * 256 + h * 8);
            float c0 = __uint_as_float(rA.y), c1 = __uint_as_float(rA.z);
            a0 += c0 * bflo(uA.x) + c1 * bflo(uA.y);
            a1 += c0 * bfhi(uA.x) + c1 * bfhi(uA.y);
            a2 += c0 * bflo(uA.z) + c1 * bflo(uA.w);
            a3 += c0 * bfhi(uA.z) + c1 * bfhi(uA.w);
            float d0 = __uint_as_float(rB.y), d1 = __uint_as_float(rB.z);
            a0 += d0 * bflo(uB.x) + d1 * bflo(uB.y);
            a1 += d0 * bfhi(uB.x) + d1 * bfhi(uB.y);
            a2 += d0 * bflo(uB.z) + d1 * bflo(uB.w);
            a3 += d0 * bfhi(uB.z) + d1 * bfhi(uB.w);
        }
        for (; i < len; i += 2) {
            int e = i + half;
            bool valid = e < len;
            uint4 r = recs[start + (valid ? e : i)];
            float c0 = valid ? __uint_as_float(r.y) : 0.f;
            float c1 = valid ? __uint_as_float(r.z) : 0.f;
            uint4 u = *(const uint4*)(mAllb + (size_t)r.x * 256 + h * 8);
            a0 += c0 * bflo(u.x) + c1 * bflo(u.y);
            a1 += c0 * bfhi(u.x) + c1 * bfhi(u.y);
            a2 += c0 * bflo(u.z) + c1 * bflo(u.w);
            a3 += c0 * bfhi(u.z) + c1 * bfhi(u.w);
        }
        a0 += __shfl_xor(a0, 32);
        a1 += __shfl_xor(a1, 32);
        a2 += __shfl_xor(a2, 32);
        a3 += __shfl_xor(a3, 32);
        if (half == 0) {
            float4* op = (float4*)(out + (size_t)d * DFEAT + h * 4);
            float4 p = *op;
            p.x = fmaxf(p.x + a0, 0.f);
            p.y = fmaxf(p.y + a1, 0.f);
            p.z = fmaxf(p.z + a2, 0.f);
            p.w = fmaxf(p.w + a3, 0.f);
            *op = p;
        }
    }
}

extern "C" void kernel_launch(void* const* d_in, const int* in_sizes, int n_in,
                              void* d_out, int out_size, void* d_ws, size_t ws_size,
                              hipStream_t stream) {
    const float* x     = (const float*)d_in[0];
    const int*   src   = (const int*)  d_in[1];
    const int*   dst   = (const int*)  d_in[2];
    const float* coeff = (const float*)d_in[3];
    const float* bases = (const float*)d_in[4];
    const float* loopw = (const float*)d_in[5];
    const float* bias  = (const float*)d_in[6];
    float* out = (float*)d_out;

    const int N  = in_sizes[0] / DFEAT;            // 100000
    const int RE = in_sizes[1];                    // R*E = 1200000
    const int B  = in_sizes[4] / (DFEAT * DFEAT);  // 2
    const int R  = in_sizes[3] / B;                // 8
    const int E  = RE / R;                         // 150000
    const int NB = (N + 1023) / 1024;              // scan blocks

    // workspace layout
    char* ws = (char*)d_ws;
    size_t off = 0;
    auto alloc = [&](size_t bytes) { void* p = ws + off; off = (off + bytes + 255) & ~(size_t)255; return p; };
    int*    deg      = (int*)   alloc((size_t)R * N * sizeof(int));   // 3.2 MB, zeroed
    size_t zero_bytes = off;
    ushort* rank     = (ushort*)alloc((size_t)RE * sizeof(ushort));   // 2.4 MB
    ushort* offsetR  = (ushort*)alloc((size_t)R * N * sizeof(ushort));// 1.6 MB
    int*    cnt      = (int*)   alloc((size_t)N * sizeof(int));
    int*    rowStart = (int*)   alloc((size_t)N * sizeof(int));
    int*    bsums    = (int*)   alloc((size_t)NB * sizeof(int));
    ushort* wcatT    = (ushort*)alloc((size_t)384 * DFEAT * sizeof(ushort));
    uint4*  recs     = (uint4*) alloc((size_t)RE * sizeof(uint4));           // 19.2 MB
    ushort* mAllb    = (ushort*)alloc((size_t)N * 256 * sizeof(ushort));     // 51.2 MB

    hipMemsetAsync(d_ws, 0, zero_bytes, stream);
    build_wcatT<<<(384 * DFEAT + 255) / 256, 256, 0, stream>>>(bases, loopw, wcatT);
    count_rank_kernel<<<(RE + 255) / 256, 256, 0, stream>>>(dst, deg, rank, RE, E, N);
    scan_block_sums<<<NB, 256, 0, stream>>>(deg, cnt, offsetR, bsums, N);
    scan_mid<<<1, 256, 0, stream>>>(bsums, NB);
    scan_write<<<NB, 256, 0, stream>>>(cnt, bsums, rowStart, N);
    fill_kernel<<<(RE + 255) / 256, 256, 0, stream>>>(src, dst, coeff, deg, rank,
                                                      offsetR, rowStart, recs, RE, E, N);

    mfma_gemm<<<(N + 63) / 64, 256, 0, stream>>>(x, wcatT, bias, mAllb, out, N);

    gather_kernel<<<4096, 256, 0, stream>>>(recs, rowStart, cnt, mAllb, out, N);
}

// Round 8
// 322.441 us; speedup vs baseline: 2.5177x; 1.0943x over previous
//
#include <hip/hip_runtime.h>
#include <hip/hip_fp16.h>

// ---------------------------------------------------------------------------
// RelGraphConv (basis-decomposed, right-norm, sum over relations) on MI355X.
//
// R8 = R7 algebra with the gemm_final staging-count fix (R3's bug pattern:
// a 128-ushort k-tile row is 16 uint4 chunks, not 8).
//   h[d] = B0^T * A0[d] + B1^T * A1[d] + x[d]@Wl + bias,  ReLU
//   A_b[d] = sum_{edges e->d} (coeff[r_e][b]/deg[r_e][d]) * x[src_e]
// Pipeline: convert x->bf16; counting-sort edges by dst (atomic-free fill via
// rank=atomic return value); gather xb rows (256B/edge, 25.6MB working set)
// into aggb[N,256] bf16; one MFMA GEMM [aggb|xb][N,384] @ w2T -> out.
// ---------------------------------------------------------------------------

#define DFEAT 128
#define LDA 136   // LDS row stride in ushorts (128 data + 8 pad)
#define NREL 8

typedef __attribute__((ext_vector_type(8))) short bf16x8;
typedef __attribute__((ext_vector_type(4))) float f32x4;

__device__ __forceinline__ ushort f2bf(float f) {
    unsigned u = __float_as_uint(f);
    u += 0x7FFF + ((u >> 16) & 1);          // round-to-nearest-even
    return (ushort)(u >> 16);
}
// packed bf16 pair -> floats: low = u<<16, high = u & 0xffff0000
__device__ __forceinline__ float bflo(unsigned u) { return __uint_as_float(u << 16); }
__device__ __forceinline__ float bfhi(unsigned u) { return __uint_as_float(u & 0xFFFF0000u); }

// w2T[j][k] bf16, j in [0,128), k in [0,384):
// k<128 -> bases[0][k][j]; k<256 -> bases[1][k-128][j]; else loopw[k-256][j]
__global__ void build_w2T(const float* __restrict__ bases,
                          const float* __restrict__ loopw,
                          ushort* __restrict__ w2T) {
    int idx = blockIdx.x * blockDim.x + threadIdx.x;
    if (idx >= 128 * 384) return;
    int j = idx / 384, k = idx % 384;
    float v;
    if (k < 256) v = bases[(k >> 7) * DFEAT * DFEAT + (k & 127) * DFEAT + j];
    else         v = loopw[(k - 256) * DFEAT + j];
    w2T[idx] = f2bf(v);
}

__global__ void convert_x(const float* __restrict__ x, ushort* __restrict__ xb, int n4) {
    int i = blockIdx.x * blockDim.x + threadIdx.x;
    if (i >= n4) return;
    float4 v = ((const float4*)x)[i];
    ushort4 o;
    o.x = f2bf(v.x); o.y = f2bf(v.y); o.z = f2bf(v.z); o.w = f2bf(v.w);
    ((ushort4*)xb)[i] = o;
}

// deg[r*N+d] int atomics; return value = rank of this edge within (r,d).
__global__ void count_rank_kernel(const int* __restrict__ dst,
                                  int* __restrict__ deg, ushort* __restrict__ rank,
                                  int RE, int E, int N) {
    int idx = blockIdx.x * blockDim.x + threadIdx.x;
    if (idx >= RE) return;
    int r = idx / E;
    int d = dst[idx];
    int old = atomicAdd(&deg[r * N + d], 1);
    rank[idx] = (ushort)old;
}

// Per 1024-node chunk: cnt[d] = sum_r deg[r][d]; offsetR[r][d] = prefix over r;
// bsums[b] = sum of cnt in chunk.
__global__ void scan_block_sums(const int* __restrict__ deg, int* __restrict__ cnt,
                                ushort* __restrict__ offsetR, int* __restrict__ bsums,
                                int N) {
    __shared__ int sdata[256];
    int b = blockIdx.x, t = threadIdx.x;
    int sum = 0;
    for (int j = 0; j < 4; ++j) {
        int idx = b * 1024 + j * 256 + t;
        if (idx < N) {
            int tot = 0;
            #pragma unroll
            for (int r = 0; r < NREL; ++r) {
                int dv = deg[r * N + idx];
                offsetR[r * N + idx] = (ushort)tot;
                tot += dv;
            }
            cnt[idx] = tot;
            sum += tot;
        }
    }
    sdata[t] = sum; __syncthreads();
    for (int s = 128; s > 0; s >>= 1) {
        if (t < s) sdata[t] += sdata[t + s];
        __syncthreads();
    }
    if (t == 0) bsums[b] = sdata[0];
}

// single-block exclusive scan of bsums[nb], nb <= 1024
__global__ void scan_mid(int* __restrict__ bsums, int nb) {
    __shared__ int s[256];
    int t = threadIdx.x;
    int base = t * 4;
    int v[4]; int sum = 0;
    #pragma unroll
    for (int i = 0; i < 4; ++i) {
        v[i] = sum;
        int c = (base + i < nb) ? bsums[base + i] : 0;
        sum += c;
    }
    s[t] = sum; __syncthreads();
    for (int off = 1; off < 256; off <<= 1) {
        int add = (t >= off) ? s[t - off] : 0;
        __syncthreads();
        s[t] += add;
        __syncthreads();
    }
    int excl = (t == 0) ? 0 : s[t - 1];
    #pragma unroll
    for (int i = 0; i < 4; ++i)
        if (base + i < nb) bsums[base + i] = excl + v[i];
}

__global__ void scan_write(const int* __restrict__ cnt, const int* __restrict__ bsums,
                           int* __restrict__ rowStart, int N) {
    __shared__ int tsum[256];
    int b = blockIdx.x, t = threadIdx.x;
    int base = b * 1024 + t * 4;
    int v[4];
    int s = 0;
    #pragma unroll
    for (int i = 0; i < 4; ++i) {
        int idx = base + i;
        v[i] = s;
        int c = (idx < N) ? cnt[idx] : 0;
        s += c;
    }
    tsum[t] = s; __syncthreads();
    for (int off = 1; off < 256; off <<= 1) {
        int x = 0;
        if (t >= off) x = tsum[t - off];
        __syncthreads();
        if (t >= off) tsum[t] += x;
        __syncthreads();
    }
    int excl = (t == 0) ? 0 : tsum[t - 1];
    int boff = bsums[b];
    #pragma unroll
    for (int i = 0; i < 4; ++i) {
        int idx = base + i;
        if (idx < N) rowStart[idx] = boff + excl + v[i];
    }
}

// Atomic-free placement: pos = rowStart[d] + offsetR[r][d] + rank[idx].
// Record (8B): {src, half2(c0,c1)}, c_b = coeff[r][b]/deg[r][d].
__global__ void fill_kernel(const int* __restrict__ src, const int* __restrict__ dst,
                            const float* __restrict__ coeff, const int* __restrict__ deg,
                            const ushort* __restrict__ rank, const ushort* __restrict__ offsetR,
                            const int* __restrict__ rowStart,
                            uint2* __restrict__ recs, int RE, int E, int N) {
    int idx = blockIdx.x * blockDim.x + threadIdx.x;
    if (idx >= RE) return;
    int r = idx / E;
    int d = dst[idx];
    int pos = rowStart[d] + offsetR[r * N + d] + rank[idx];
    float inv = 1.0f / (float)deg[r * N + d];
    __half2 hc = __floats2half2_rn(coeff[2 * r] * inv, coeff[2 * r + 1] * inv);
    uint2 rec;
    rec.x = (unsigned)src[idx];
    rec.y = *(unsigned*)&hc;
    recs[pos] = rec;
}

// Half-wave per edge: lanes 0-31 edge i, lanes 32-63 edge i+1; lane h owns
// features 4h..4h+3 of xb[src] (one uint2). Dual accumulators (c0-side a*,
// c1-side b*). 2x unrolled. After shfl reduction, half0 writes A0 chunk,
// half1 writes A1 chunk -> one contiguous 512B aggb row per wave.
__global__ __launch_bounds__(256) void gather_kernel(
    const uint2* __restrict__ recs, const int* __restrict__ rowStart,
    const int* __restrict__ cnt, const ushort* __restrict__ xb,
    ushort* __restrict__ aggb, int N) {
    const int lane = threadIdx.x & 63;
    const int half = lane >> 5;
    const int h = lane & 31;
    const int wave = (blockIdx.x * blockDim.x + threadIdx.x) >> 6;
    const int nwaves = (gridDim.x * blockDim.x) >> 6;
    for (int d = wave; d < N; d += nwaves) {
        float a0 = 0.f, a1 = 0.f, a2 = 0.f, a3 = 0.f;   // c0 side
        float b0 = 0.f, b1 = 0.f, b2 = 0.f, b3 = 0.f;   // c1 side
        const int start = rowStart[d];
        const int len = cnt[d];
        int i = 0;
        for (; i + 4 <= len; i += 4) {
            uint2 rA = recs[start + i + half];
            uint2 rB = recs[start + i + 2 + half];
            uint2 uA = *(const uint2*)(xb + (size_t)rA.x * DFEAT + h * 4);
            uint2 uB = *(const uint2*)(xb + (size_t)rB.x * DFEAT + h * 4);
            __half2 hA = *(__half2*)&rA.y;
            float c0 = __low2float(hA), c1 = __high2float(hA);
            float f0 = bflo(uA.x), f1 = bfhi(uA.x), f2 = bflo(uA.y), f3 = bfhi(uA.y);
            a0 += c0 * f0; a1 += c0 * f1; a2 += c0 * f2; a3 += c0 * f3;
            b0 += c1 * f0; b1 += c1 * f1; b2 += c1 * f2; b3 += c1 * f3;
            __half2 hB = *(__half2*)&rB.y;
            float d0 = __low2float(hB), d1 = __high2float(hB);
            float g0 = bflo(uB.x), g1 = bfhi(uB.x), g2 = bflo(uB.y), g3 = bfhi(uB.y);
            a0 += d0 * g0; a1 += d0 * g1; a2 += d0 * g2; a3 += d0 * g3;
            b0 += d1 * g0; b1 += d1 * g1; b2 += d1 * g2; b3 += d1 * g3;
        }
        for (; i < len; i += 2) {
            int e = i + half;
            bool valid = e < len;
            uint2 r = recs[start + (valid ? e : i)];
            __half2 hr = *(__half2*)&r.y;
            float c0 = valid ? __low2float(hr) : 0.f;
            float c1 = valid ? __high2float(hr) : 0.f;
            uint2 u = *(const uint2*)(xb + (size_t)r.x * DFEAT + h * 4);
            float f0 = bflo(u.x), f1 = bfhi(u.x), f2 = bflo(u.y), f3 = bfhi(u.y);
            a0 += c0 * f0; a1 += c0 * f1; a2 += c0 * f2; a3 += c0 * f3;
            b0 += c1 * f0; b1 += c1 * f1; b2 += c1 * f2; b3 += c1 * f3;
        }
        a0 += __shfl_xor(a0, 32); a1 += __shfl_xor(a1, 32);
        a2 += __shfl_xor(a2, 32); a3 += __shfl_xor(a3, 32);
        b0 += __shfl_xor(b0, 32); b1 += __shfl_xor(b1, 32);
        b2 += __shfl_xor(b2, 32); b3 += __shfl_xor(b3, 32);
        float o0 = half ? b0 : a0, o1 = half ? b1 : a1;
        float o2 = half ? b2 : a2, o3 = half ? b3 : a3;
        ushort4 o = make_ushort4(f2bf(o0), f2bf(o1), f2bf(o2), f2bf(o3));
        // half0 lane h -> A0 feats 4h..4h+3 (offset lane*4);
        // half1 lane h -> A1 feats 4h..4h+3 (offset 128+4h = lane*4). Contiguous.
        *(ushort4*)(aggb + (size_t)d * 256 + lane * 4) = o;
    }
}

// ---------------------------------------------------------------------------
// Final MFMA GEMM: out[N,128] = relu([aggb|xb][N,384] @ w2T^T + bias)
// Block: 64 rows x 128 cols, 3 K-tiles of 128. LDS ~52KB.
// Staging: 64-row tile = 1024 uint4 chunks (16/row); 128-row = 2048.
// ---------------------------------------------------------------------------
__global__ __launch_bounds__(256) void gemm_final(
    const ushort* __restrict__ aggb, const ushort* __restrict__ xb,
    const ushort* __restrict__ w2T, const float* __restrict__ bias,
    float* __restrict__ out, int Nrows) {
    __shared__ __align__(16) ushort Als[64 * LDA];
    __shared__ __align__(16) ushort Bls[128 * LDA];
    const int tid = threadIdx.x;
    const int wave = tid >> 6, lane = tid & 63;
    const int quad = lane >> 4, l16 = lane & 15;
    const int row0 = blockIdx.x * 64;

    f32x4 zero = {0.f, 0.f, 0.f, 0.f};
    f32x4 acc[8] = {zero, zero, zero, zero, zero, zero, zero, zero};

    for (int kt = 0; kt < 3; ++kt) {
        // stage A k-tile: 64 rows x 16 chunks(16B) = 1024
        for (int c = tid; c < 1024; c += 256) {
            int r = c >> 4, seg = c & 15;
            int grow = row0 + r; if (grow >= Nrows) grow = 0;
            const ushort* sp = (kt < 2) ? (aggb + (size_t)grow * 256 + kt * 128 + seg * 8)
                                        : (xb + (size_t)grow * DFEAT + seg * 8);
            *(uint4*)(Als + r * LDA + seg * 8) = *(const uint4*)sp;
        }
        // stage B k-tile: 128 j-rows x 16 chunks = 2048
        for (int c = tid; c < 2048; c += 256) {
            int j = c >> 4, seg = c & 15;
            uint4 v = *(const uint4*)(w2T + (size_t)j * 384 + kt * 128 + seg * 8);
            *(uint4*)(Bls + j * LDA + seg * 8) = v;
        }
        __syncthreads();

        #pragma unroll
        for (int t = 0; t < 4; ++t) {
            int k0 = t * 32 + quad * 8;
            bf16x8 a = *(const bf16x8*)(Als + (wave * 16 + l16) * LDA + k0);
            #pragma unroll
            for (int g = 0; g < 8; ++g) {
                bf16x8 b = *(const bf16x8*)(Bls + (g * 16 + l16) * LDA + k0);
                acc[g] = __builtin_amdgcn_mfma_f32_16x16x32_bf16(a, b, acc[g], 0, 0, 0);
            }
        }
        __syncthreads();
    }

    #pragma unroll
    for (int g = 0; g < 8; ++g) {
        int c = g * 16 + l16;
        float bv = bias[c];
        #pragma unroll
        for (int reg = 0; reg < 4; ++reg) {
            int grow = row0 + wave * 16 + quad * 4 + reg;
            if (grow < Nrows)
                out[(size_t)grow * DFEAT + c] = fmaxf(acc[g][reg] + bv, 0.f);
        }
    }
}

extern "C" void kernel_launch(void* const* d_in, const int* in_sizes, int n_in,
                              void* d_out, int out_size, void* d_ws, size_t ws_size,
                              hipStream_t stream) {
    const float* x     = (const float*)d_in[0];
    const int*   src   = (const int*)  d_in[1];
    const int*   dst   = (const int*)  d_in[2];
    const float* coeff = (const float*)d_in[3];
    const float* bases = (const float*)d_in[4];
    const float* loopw = (const float*)d_in[5];
    const float* bias  = (const float*)d_in[6];
    float* out = (float*)d_out;

    const int N  = in_sizes[0] / DFEAT;            // 100000
    const int RE = in_sizes[1];                    // R*E = 1200000
    const int B  = in_sizes[4] / (DFEAT * DFEAT);  // 2
    const int R  = in_sizes[3] / B;                // 8
    const int E  = RE / R;                         // 150000
    const int NB = (N + 1023) / 1024;              // scan blocks

    // workspace layout
    char* ws = (char*)d_ws;
    size_t off = 0;
    auto alloc = [&](size_t bytes) { void* p = ws + off; off = (off + bytes + 255) & ~(size_t)255; return p; };
    int*    deg      = (int*)   alloc((size_t)R * N * sizeof(int));   // 3.2 MB, zeroed
    size_t zero_bytes = off;
    ushort* rank     = (ushort*)alloc((size_t)RE * sizeof(ushort));   // 2.4 MB
    ushort* offsetR  = (ushort*)alloc((size_t)R * N * sizeof(ushort));// 1.6 MB
    int*    cnt      = (int*)   alloc((size_t)N * sizeof(int));
    int*    rowStart = (int*)   alloc((size_t)N * sizeof(int));
    int*    bsums    = (int*)   alloc((size_t)NB * sizeof(int));
    ushort* w2T      = (ushort*)alloc((size_t)128 * 384 * sizeof(ushort));
    ushort* xb       = (ushort*)alloc((size_t)N * DFEAT * sizeof(ushort));   // 25.6 MB
    uint2*  recs     = (uint2*) alloc((size_t)RE * sizeof(uint2));           // 9.6 MB
    ushort* aggb     = (ushort*)alloc((size_t)N * 256 * sizeof(ushort));     // 51.2 MB

    hipMemsetAsync(d_ws, 0, zero_bytes, stream);
    build_w2T<<<(128 * 384 + 255) / 256, 256, 0, stream>>>(bases, loopw, w2T);
    convert_x<<<(N * 32 + 255) / 256, 256, 0, stream>>>(x, xb, N * 32);
    count_rank_kernel<<<(RE + 255) / 256, 256, 0, stream>>>(dst, deg, rank, RE, E, N);
    scan_block_sums<<<NB, 256, 0, stream>>>(deg, cnt, offsetR, bsums, N);
    scan_mid<<<1, 256, 0, stream>>>(bsums, NB);
    scan_write<<<NB, 256, 0, stream>>>(cnt, bsums, rowStart, N);
    fill_kernel<<<(RE + 255) / 256, 256, 0, stream>>>(src, dst, coeff, deg, rank,
                                                      offsetR, rowStart, recs, RE, E, N);

    gather_kernel<<<4096, 256, 0, stream>>>(recs, rowStart, cnt, xb, aggb, N);

    gemm_final<<<(N + 63) / 64, 256, 0, stream>>>(aggb, xb, w2T, bias, out, N);
}

// Round 9
// 310.562 us; speedup vs baseline: 2.6140x; 1.0383x over previous
//
#include <hip/hip_runtime.h>
#include <hip/hip_fp16.h>

// ---------------------------------------------------------------------------
// RelGraphConv (basis-decomposed, right-norm, sum over relations) on MI355X.
//
//   h[d] = B0^T * A0[d] + B1^T * A1[d] + x[d]@Wl + bias,  ReLU
//   A_b[d] = sum_{edges e->d} (coeff[r_e][b]/deg[r_e][d]) * x[src_e]
// R9: gather unroll x4 + v_pk_fma_f32 (float2 accum); fill uses one packed
// random read (basePos<<11|deg); init fusion (memset+w2T+convert in one).
// ---------------------------------------------------------------------------

#define DFEAT 128
#define LDA 136   // LDS row stride in ushorts (128 data + 8 pad)
#define NREL 8

typedef __attribute__((ext_vector_type(8))) short bf16x8;
typedef __attribute__((ext_vector_type(4))) float f32x4;
typedef __attribute__((ext_vector_type(2))) float f32x2;

__device__ __forceinline__ ushort f2bf(float f) {
    unsigned u = __float_as_uint(f);
    u += 0x7FFF + ((u >> 16) & 1);          // round-to-nearest-even
    return (ushort)(u >> 16);
}
__device__ __forceinline__ float bflo(unsigned u) { return __uint_as_float(u << 16); }
__device__ __forceinline__ float bfhi(unsigned u) { return __uint_as_float(u & 0xFFFF0000u); }

// Fused init: zero deg; build w2T; convert x->bf16.
// w2T[j][k]: k<256 -> bases[k>>7][k&127][j]; else loopw[k-256][j]
__global__ void init_kernel(const float* __restrict__ x, ushort* __restrict__ xb,
                            const float* __restrict__ bases, const float* __restrict__ loopw,
                            ushort* __restrict__ w2T, int* __restrict__ deg,
                            int n4, int RN) {
    const int stride = gridDim.x * blockDim.x;
    const int t0 = blockIdx.x * blockDim.x + threadIdx.x;
    for (int i = t0; i < n4; i += stride) {
        float4 v = ((const float4*)x)[i];
        ushort4 o;
        o.x = f2bf(v.x); o.y = f2bf(v.y); o.z = f2bf(v.z); o.w = f2bf(v.w);
        ((ushort4*)xb)[i] = o;
    }
    for (int i = t0; i < 128 * 384; i += stride) {
        int j = i / 384, k = i % 384;
        float v = (k < 256) ? bases[(k >> 7) * DFEAT * DFEAT + (k & 127) * DFEAT + j]
                            : loopw[(k - 256) * DFEAT + j];
        w2T[i] = f2bf(v);
    }
    for (int i = t0; i < RN; i += stride) deg[i] = 0;
}

// deg[r*N+d] int atomics; return value = rank of this edge within (r,d).
__global__ void count_rank_kernel(const int* __restrict__ dst,
                                  int* __restrict__ deg, ushort* __restrict__ rank,
                                  int RE, int E, int N) {
    int idx = blockIdx.x * blockDim.x + threadIdx.x;
    if (idx >= RE) return;
    int r = idx / E;
    int d = dst[idx];
    int old = atomicAdd(&deg[r * N + d], 1);
    rank[idx] = (ushort)old;
}

// Per 1024-node chunk: cnt[d] = sum_r deg[r][d]; bsums[b] = chunk total.
__global__ void scan_block_sums(const int* __restrict__ deg, int* __restrict__ cnt,
                                int* __restrict__ bsums, int N) {
    __shared__ int sdata[256];
    int b = blockIdx.x, t = threadIdx.x;
    int sum = 0;
    for (int j = 0; j < 4; ++j) {
        int idx = b * 1024 + j * 256 + t;
        if (idx < N) {
            int tot = 0;
            #pragma unroll
            for (int r = 0; r < NREL; ++r) tot += deg[r * N + idx];
            cnt[idx] = tot;
            sum += tot;
        }
    }
    sdata[t] = sum; __syncthreads();
    for (int s = 128; s > 0; s >>= 1) {
        if (t < s) sdata[t] += sdata[t + s];
        __syncthreads();
    }
    if (t == 0) bsums[b] = sdata[0];
}

// single-block exclusive scan of bsums[nb], nb <= 1024
__global__ void scan_mid(int* __restrict__ bsums, int nb) {
    __shared__ int s[256];
    int t = threadIdx.x;
    int base = t * 4;
    int v[4]; int sum = 0;
    #pragma unroll
    for (int i = 0; i < 4; ++i) {
        v[i] = sum;
        int c = (base + i < nb) ? bsums[base + i] : 0;
        sum += c;
    }
    s[t] = sum; __syncthreads();
    for (int off = 1; off < 256; off <<= 1) {
        int add = (t >= off) ? s[t - off] : 0;
        __syncthreads();
        s[t] += add;
        __syncthreads();
    }
    int excl = (t == 0) ? 0 : s[t - 1];
    #pragma unroll
    for (int i = 0; i < 4; ++i)
        if (base + i < nb) bsums[base + i] = excl + v[i];
}

// rowStart[d] (for gather) + packed[r*N+d] = ((rowStart[d]+prefix_r)<<11)|deg
// (basePos <= 1.2M fits 21 bits; per-(r,d) deg << 2048 at E/N=1.5 avg).
__global__ void scan_write(const int* __restrict__ cnt, const int* __restrict__ bsums,
                           const int* __restrict__ deg,
                           int* __restrict__ rowStart, unsigned* __restrict__ packed,
                           int N) {
    __shared__ int tsum[256];
    int b = blockIdx.x, t = threadIdx.x;
    int base = b * 1024 + t * 4;
    int v[4];
    int s = 0;
    #pragma unroll
    for (int i = 0; i < 4; ++i) {
        int idx = base + i;
        v[i] = s;
        int c = (idx < N) ? cnt[idx] : 0;
        s += c;
    }
    tsum[t] = s; __syncthreads();
    for (int off = 1; off < 256; off <<= 1) {
        int x = 0;
        if (t >= off) x = tsum[t - off];
        __syncthreads();
        if (t >= off) tsum[t] += x;
        __syncthreads();
    }
    int excl = (t == 0) ? 0 : tsum[t - 1];
    int boff = bsums[b];
    #pragma unroll
    for (int i = 0; i < 4; ++i) {
        int idx = base + i;
        if (idx < N) {
            int rs = boff + excl + v[i];
            rowStart[idx] = rs;
            int pre = 0;
            #pragma unroll
            for (int r = 0; r < NREL; ++r) {
                int dv = deg[r * N + idx];
                packed[r * N + idx] = ((unsigned)(rs + pre) << 11) | (unsigned)dv;
                pre += dv;
            }
        }
    }
}

// Atomic-free placement: pos = (packed>>11) + rank. ONE random read per edge.
// Record (8B): {src, half2(c0,c1)}, c_b = coeff[r][b]/deg[r][d].
__global__ void fill_kernel(const int* __restrict__ src, const int* __restrict__ dst,
                            const float* __restrict__ coeff,
                            const ushort* __restrict__ rank,
                            const unsigned* __restrict__ packed,
                            uint2* __restrict__ recs, int RE, int E, int N) {
    int idx = blockIdx.x * blockDim.x + threadIdx.x;
    if (idx >= RE) return;
    int r = idx / E;
    int d = dst[idx];
    unsigned p = packed[r * N + d];
    int pos = (int)(p >> 11) + (int)rank[idx];
    float inv = 1.0f / (float)(p & 2047u);
    __half2 hc = __floats2half2_rn(coeff[2 * r] * inv, coeff[2 * r + 1] * inv);
    uint2 rec;
    rec.x = (unsigned)src[idx];
    rec.y = *(unsigned*)&hc;
    recs[pos] = rec;
}

// Half-wave per edge, 4 edge-pairs unrolled (8 loads in flight). Accumulators
// are float2 vectors -> v_pk_fma_f32 (2 FMA/inst). After xor32 reduction,
// half0 writes A0 chunk, half1 writes A1 chunk (contiguous 512B aggb row).
__global__ __launch_bounds__(256) void gather_kernel(
    const uint2* __restrict__ recs, const int* __restrict__ rowStart,
    const int* __restrict__ cnt, const ushort* __restrict__ xb,
    ushort* __restrict__ aggb, int N) {
    const int lane = threadIdx.x & 63;
    const int half = lane >> 5;
    const int h = lane & 31;
    const int wave = (blockIdx.x * blockDim.x + threadIdx.x) >> 6;
    const int nwaves = (gridDim.x * blockDim.x) >> 6;
    for (int d = wave; d < N; d += nwaves) {
        f32x2 A0 = {0.f, 0.f}, A1 = {0.f, 0.f};   // c0 side, feats (4h,4h+1),(4h+2,4h+3)
        f32x2 B0 = {0.f, 0.f}, B1 = {0.f, 0.f};   // c1 side
        const int start = rowStart[d];
        const int len = cnt[d];
        int i = 0;
        for (; i + 8 <= len; i += 8) {
            uint2 r0 = recs[start + i + half];
            uint2 r1 = recs[start + i + 2 + half];
            uint2 r2 = recs[start + i + 4 + half];
            uint2 r3 = recs[start + i + 6 + half];
            uint2 u0 = *(const uint2*)(xb + (size_t)r0.x * DFEAT + h * 4);
            uint2 u1 = *(const uint2*)(xb + (size_t)r1.x * DFEAT + h * 4);
            uint2 u2 = *(const uint2*)(xb + (size_t)r2.x * DFEAT + h * 4);
            uint2 u3 = *(const uint2*)(xb + (size_t)r3.x * DFEAT + h * 4);
            #pragma unroll
            for (int q = 0; q < 4; ++q) {
                uint2 rr = q == 0 ? r0 : q == 1 ? r1 : q == 2 ? r2 : r3;
                uint2 uu = q == 0 ? u0 : q == 1 ? u1 : q == 2 ? u2 : u3;
                __half2 hc = *(__half2*)&rr.y;
                float c0 = __low2float(hc), c1 = __high2float(hc);
                f32x2 cc0 = {c0, c0}, cc1 = {c1, c1};
                f32x2 f01 = {bflo(uu.x), bfhi(uu.x)};
                f32x2 f23 = {bflo(uu.y), bfhi(uu.y)};
                A0 += cc0 * f01; A1 += cc0 * f23;
                B0 += cc1 * f01; B1 += cc1 * f23;
            }
        }
        for (; i < len; i += 2) {
            int e = i + half;
            bool valid = e < len;
            uint2 rr = recs[start + (valid ? e : i)];
            __half2 hc = *(__half2*)&rr.y;
            float c0 = valid ? __low2float(hc) : 0.f;
            float c1 = valid ? __high2float(hc) : 0.f;
            uint2 uu = *(const uint2*)(xb + (size_t)rr.x * DFEAT + h * 4);
            f32x2 cc0 = {c0, c0}, cc1 = {c1, c1};
            f32x2 f01 = {bflo(uu.x), bfhi(uu.x)};
            f32x2 f23 = {bflo(uu.y), bfhi(uu.y)};
            A0 += cc0 * f01; A1 += cc0 * f23;
            B0 += cc1 * f01; B1 += cc1 * f23;
        }
        A0.x += __shfl_xor(A0.x, 32); A0.y += __shfl_xor(A0.y, 32);
        A1.x += __shfl_xor(A1.x, 32); A1.y += __shfl_xor(A1.y, 32);
        B0.x += __shfl_xor(B0.x, 32); B0.y += __shfl_xor(B0.y, 32);
        B1.x += __shfl_xor(B1.x, 32); B1.y += __shfl_xor(B1.y, 32);
        f32x2 O01 = half ? B0 : A0;
        f32x2 O23 = half ? B1 : A1;
        ushort4 o = make_ushort4(f2bf(O01.x), f2bf(O01.y), f2bf(O23.x), f2bf(O23.y));
        *(ushort4*)(aggb + (size_t)d * 256 + lane * 4) = o;
    }
}

// ---------------------------------------------------------------------------
// Final MFMA GEMM: out[N,128] = relu([aggb|xb][N,384] @ w2T^T + bias)
// Block: 64 rows x 128 cols, 3 K-tiles of 128. 64-row tile = 1024 uint4
// chunks (16/row); 128-row = 2048.
// ---------------------------------------------------------------------------
__global__ __launch_bounds__(256) void gemm_final(
    const ushort* __restrict__ aggb, const ushort* __restrict__ xb,
    const ushort* __restrict__ w2T, const float* __restrict__ bias,
    float* __restrict__ out, int Nrows) {
    __shared__ __align__(16) ushort Als[64 * LDA];
    __shared__ __align__(16) ushort Bls[128 * LDA];
    const int tid = threadIdx.x;
    const int wave = tid >> 6, lane = tid & 63;
    const int quad = lane >> 4, l16 = lane & 15;
    const int row0 = blockIdx.x * 64;

    f32x4 zero = {0.f, 0.f, 0.f, 0.f};
    f32x4 acc[8] = {zero, zero, zero, zero, zero, zero, zero, zero};

    for (int kt = 0; kt < 3; ++kt) {
        for (int c = tid; c < 1024; c += 256) {
            int r = c >> 4, seg = c & 15;
            int grow = row0 + r; if (grow >= Nrows) grow = 0;
            const ushort* sp = (kt < 2) ? (aggb + (size_t)grow * 256 + kt * 128 + seg * 8)
                                        : (xb + (size_t)grow * DFEAT + seg * 8);
            *(uint4*)(Als + r * LDA + seg * 8) = *(const uint4*)sp;
        }
        for (int c = tid; c < 2048; c += 256) {
            int j = c >> 4, seg = c & 15;
            uint4 v = *(const uint4*)(w2T + (size_t)j * 384 + kt * 128 + seg * 8);
            *(uint4*)(Bls + j * LDA + seg * 8) = v;
        }
        __syncthreads();

        #pragma unroll
        for (int t = 0; t < 4; ++t) {
            int k0 = t * 32 + quad * 8;
            bf16x8 a = *(const bf16x8*)(Als + (wave * 16 + l16) * LDA + k0);
            #pragma unroll
            for (int g = 0; g < 8; ++g) {
                bf16x8 b = *(const bf16x8*)(Bls + (g * 16 + l16) * LDA + k0);
                acc[g] = __builtin_amdgcn_mfma_f32_16x16x32_bf16(a, b, acc[g], 0, 0, 0);
            }
        }
        __syncthreads();
    }

    #pragma unroll
    for (int g = 0; g < 8; ++g) {
        int c = g * 16 + l16;
        float bv = bias[c];
        #pragma unroll
        for (int reg = 0; reg < 4; ++reg) {
            int grow = row0 + wave * 16 + quad * 4 + reg;
            if (grow < Nrows)
                out[(size_t)grow * DFEAT + c] = fmaxf(acc[g][reg] + bv, 0.f);
        }
    }
}

extern "C" void kernel_launch(void* const* d_in, const int* in_sizes, int n_in,
                              void* d_out, int out_size, void* d_ws, size_t ws_size,
                              hipStream_t stream) {
    const float* x     = (const float*)d_in[0];
    const int*   src   = (const int*)  d_in[1];
    const int*   dst   = (const int*)  d_in[2];
    const float* coeff = (const float*)d_in[3];
    const float* bases = (const float*)d_in[4];
    const float* loopw = (const float*)d_in[5];
    const float* bias  = (const float*)d_in[6];
    float* out = (float*)d_out;

    const int N  = in_sizes[0] / DFEAT;            // 100000
    const int RE = in_sizes[1];                    // R*E = 1200000
    const int B  = in_sizes[4] / (DFEAT * DFEAT);  // 2
    const int R  = in_sizes[3] / B;                // 8
    const int E  = RE / R;                         // 150000
    const int NB = (N + 1023) / 1024;              // scan blocks

    // workspace layout
    char* ws = (char*)d_ws;
    size_t off = 0;
    auto alloc = [&](size_t bytes) { void* p = ws + off; off = (off + bytes + 255) & ~(size_t)255; return p; };
    int*      deg      = (int*)     alloc((size_t)R * N * sizeof(int));     // 3.2 MB
    ushort*   rank     = (ushort*)  alloc((size_t)RE * sizeof(ushort));     // 2.4 MB
    unsigned* packed   = (unsigned*)alloc((size_t)R * N * sizeof(unsigned));// 3.2 MB
    int*      cnt      = (int*)     alloc((size_t)N * sizeof(int));
    int*      rowStart = (int*)     alloc((size_t)N * sizeof(int));
    int*      bsums    = (int*)     alloc((size_t)NB * sizeof(int));
    ushort*   w2T      = (ushort*)  alloc((size_t)128 * 384 * sizeof(ushort));
    ushort*   xb       = (ushort*)  alloc((size_t)N * DFEAT * sizeof(ushort)); // 25.6 MB
    uint2*    recs     = (uint2*)   alloc((size_t)RE * sizeof(uint2));         // 9.6 MB
    ushort*   aggb     = (ushort*)  alloc((size_t)N * 256 * sizeof(ushort));   // 51.2 MB

    init_kernel<<<4096, 256, 0, stream>>>(x, xb, bases, loopw, w2T, deg, N * 32, R * N);
    count_rank_kernel<<<(RE + 255) / 256, 256, 0, stream>>>(dst, deg, rank, RE, E, N);
    scan_block_sums<<<NB, 256, 0, stream>>>(deg, cnt, bsums, N);
    scan_mid<<<1, 256, 0, stream>>>(bsums, NB);
    scan_write<<<NB, 256, 0, stream>>>(cnt, bsums, deg, rowStart, packed, N);
    fill_kernel<<<(RE + 255) / 256, 256, 0, stream>>>(src, dst, coeff, rank, packed,
                                                      recs, RE, E, N);

    gather_kernel<<<4096, 256, 0, stream>>>(recs, rowStart, cnt, xb, aggb, N);

    gemm_final<<<(N + 63) / 64, 256, 0, stream>>>(aggb, xb, w2T, bias, out, N);
}